// Round 6
// baseline (420.884 us; speedup 1.0000x reference)
//
#include <hip/hip_runtime.h>
#include <hip/hip_bf16.h>

#define F_IN 256
#define HID  64
#define CLS  40
#define EPS  1e-8f
#define XS_STRIDE 264   // halfwords per LDS x-tile row: 2-way max bank aliasing (free)
#define EPB  8192       // edges per block in hist/scatter passes (256 thr x 32)

typedef unsigned short ushort_t;
typedef unsigned int   uint_t;
typedef __attribute__((ext_vector_type(8))) short bf16x8;
typedef __attribute__((ext_vector_type(4))) float f32x4;

__device__ __forceinline__ float bf2f(ushort_t u) {
    union { uint_t i; float f; } v; v.i = ((uint_t)u) << 16; return v.f;
}
__device__ __forceinline__ ushort_t f2bf(float f) {
    union { float f; uint_t i; } v; v.f = f;
    uint_t r = v.i + 0x7fff + ((v.i >> 16) & 1);          // RNE
    return (ushort_t)(r >> 16);
}
__device__ __forceinline__ float blo(uint_t p) {
    union { uint_t i; float f; } v; v.i = p << 16; return v.f;
}
__device__ __forceinline__ float bhi(uint_t p) {
    union { uint_t i; float f; } v; v.i = p & 0xffff0000u; return v.f;
}
__device__ __forceinline__ float dot_u4(uint4 a, uint4 b) {
    return blo(a.x) * blo(b.x) + bhi(a.x) * bhi(b.x)
         + blo(a.y) * blo(b.y) + bhi(a.y) * bhi(b.y)
         + blo(a.z) * blo(b.z) + bhi(a.z) * bhi(b.z)
         + blo(a.w) * blo(b.w) + bhi(a.w) * bhi(b.w);
}

// -------------------- dtype detection (int64 vs int32 edge_index) -----------
__global__ void detect_kernel(const int* __restrict__ raw, int* __restrict__ flag) {
    int c = threadIdx.x;                  // one wave
    int w = raw[2 * c + 1];               // odd int32 words
    unsigned long long b = __ballot(w != 0);
    if (c == 0) *flag = (b == 0ULL) ? 1 : 0;   // all zero -> int64 layout
}

// ---- pass 1: pair packing + per-block bucket histogram (dst>>8) ------------
__global__ void build_hist_kernel(const void* __restrict__ raw, const int* __restrict__ flag,
                                  uint_t* __restrict__ pair, int* __restrict__ ghist, int E) {
    __shared__ int lhist[256];
    int tid = threadIdx.x;
    lhist[tid] = 0;
    __syncthreads();
    int base = blockIdx.x * EPB;
    if (*flag) {
        const long long* r = (const long long*)raw;
        for (int it = 0; it < EPB / 1024; ++it) {        // 4 edges/thread/iter
            int e = base + (it * 256 + tid) * 4;
            if (e + 4 <= E) {
                ulonglong2 a0 = *(const ulonglong2*)(r + e);
                ulonglong2 a1 = *(const ulonglong2*)(r + e + 2);
                ulonglong2 b0 = *(const ulonglong2*)(r + E + e);
                ulonglong2 b1 = *(const ulonglong2*)(r + E + e + 2);
                uint_t d0 = (uint_t)b0.x, d1 = (uint_t)b0.y;
                uint_t d2 = (uint_t)b1.x, d3 = (uint_t)b1.y;
                uint4 p;
                p.x = (d0 << 16) | (uint_t)a0.x;
                p.y = (d1 << 16) | (uint_t)a0.y;
                p.z = (d2 << 16) | (uint_t)a1.x;
                p.w = (d3 << 16) | (uint_t)a1.y;
                *(uint4*)(pair + e) = p;
                atomicAdd(&lhist[d0 >> 8], 1);
                atomicAdd(&lhist[d1 >> 8], 1);
                atomicAdd(&lhist[d2 >> 8], 1);
                atomicAdd(&lhist[d3 >> 8], 1);
            } else {
                for (int k = 0; k < 4; ++k) {
                    int ee = e + k;
                    if (ee < E) {
                        uint_t s = (uint_t)r[ee];
                        uint_t d = (uint_t)r[E + ee];
                        pair[ee] = (d << 16) | s;
                        atomicAdd(&lhist[d >> 8], 1);
                    }
                }
            }
        }
    } else {
        const int* r = (const int*)raw;
        for (int it = 0; it < EPB / 1024; ++it) {        // 4 edges/thread/iter
            int e = base + (it * 256 + tid) * 4;
            if (e + 4 <= E) {
                int4 a = *(const int4*)(r + e);
                int4 b = *(const int4*)(r + E + e);
                uint_t d0 = (uint_t)b.x, d1 = (uint_t)b.y;
                uint_t d2 = (uint_t)b.z, d3 = (uint_t)b.w;
                uint4 p;
                p.x = (d0 << 16) | (uint_t)a.x;
                p.y = (d1 << 16) | (uint_t)a.y;
                p.z = (d2 << 16) | (uint_t)a.z;
                p.w = (d3 << 16) | (uint_t)a.w;
                *(uint4*)(pair + e) = p;
                atomicAdd(&lhist[d0 >> 8], 1);
                atomicAdd(&lhist[d1 >> 8], 1);
                atomicAdd(&lhist[d2 >> 8], 1);
                atomicAdd(&lhist[d3 >> 8], 1);
            } else {
                for (int k = 0; k < 4; ++k) {
                    int ee = e + k;
                    if (ee < E) {
                        uint_t s = (uint_t)r[ee];
                        uint_t d = (uint_t)r[E + ee];
                        pair[ee] = (d << 16) | s;
                        atomicAdd(&lhist[d >> 8], 1);
                    }
                }
            }
        }
    }
    __syncthreads();
    ghist[blockIdx.x * 256 + tid] = lhist[tid];
}

// ---- pass 2a: PARALLEL column scan — one wave per bucket -------------------
__global__ void scan_cols_kernel(int* __restrict__ ghist, int* __restrict__ btot,
                                 int NBLK) {
    int k    = blockIdx.x;                 // bucket 0..255
    int lane = threadIdx.x;                // 0..63
    int carry = 0;
    for (int b0 = 0; b0 < NBLK; b0 += 64) {
        int b = b0 + lane;
        int v = (b < NBLK) ? ghist[b * 256 + k] : 0;
        int x = v;
        #pragma unroll
        for (int o = 1; o < 64; o <<= 1) {
            int t = __shfl_up(x, o);
            if (lane >= o) x += t;
        }
        if (b < NBLK) ghist[b * 256 + k] = carry + x - v;   // exclusive offset
        carry += __shfl(x, 63);            // batch total
    }
    if (lane == 0) btot[k] = carry;        // bucket total
}

// ---- pass 2b (1 block): exclusive scan of bucket totals -> bucket bases ----
__global__ void scan_base_kernel(const int* __restrict__ btot, int* __restrict__ bbase) {
    __shared__ int s[256];
    int k = threadIdx.x;
    int v = btot[k];
    int x = v;
    s[k] = x;
    __syncthreads();
    #pragma unroll
    for (int o = 1; o < 256; o <<= 1) {
        int t = (k >= o) ? s[k - o] : 0;
        __syncthreads();
        x += t;
        s[k] = x;
        __syncthreads();
    }
    bbase[k] = x - v;                      // exclusive bucket base
    if (k == 255) bbase[256] = x;          // == E
}

// ---- pass 3: scatter edges into bucket regions (LDS cursors only) ----------
__global__ void scatter_buckets_kernel(const uint_t* __restrict__ pair,
                                       const int* __restrict__ ghist,
                                       const int* __restrict__ bbase,
                                       uint_t* __restrict__ bkt, int E) {
    __shared__ int cursor[256];
    int tid = threadIdx.x;
    cursor[tid] = ghist[blockIdx.x * 256 + tid] + bbase[tid];
    __syncthreads();
    int base = blockIdx.x * EPB;
    for (int it = 0; it < EPB / 256; ++it) {
        int e = base + it * 256 + tid;
        if (e < E) {
            uint_t u = pair[e];
            int pos = atomicAdd(&cursor[u >> 24], 1);   // LDS atomic, returns rank
            bkt[pos] = u;
        }
    }
}

// ---- pass 4: one block per bucket -> deg/rowptr/dinv + sorted csr16 --------
__global__ void bucket_csr_kernel(const uint_t* __restrict__ bkt,
                                  const int* __restrict__ bbase,
                                  ushort_t* __restrict__ csr, int* __restrict__ rowptr,
                                  float* __restrict__ dinv, int n, int E, int NBUCK) {
    __shared__ int lhist[256];
    __shared__ int lscan[256];
    __shared__ int cursor[256];
    int tid = threadIdx.x;
    int kb  = blockIdx.x;
    int base = bbase[kb];
    int cnt  = bbase[kb + 1] - base;
    lhist[tid] = 0;
    __syncthreads();
    for (int i = tid; i < cnt; i += 256) {            // pass A: exact degrees
        uint_t u = bkt[base + i];
        atomicAdd(&lhist[(u >> 16) & 255], 1);
    }
    __syncthreads();
    int v = lhist[tid];                        // degree of node kb*256+tid (no self-loop)
    int x = v;
    lscan[tid] = x;
    __syncthreads();
    #pragma unroll
    for (int o = 1; o < 256; o <<= 1) {
        int t = (tid >= o) ? lscan[tid - o] : 0;
        __syncthreads();
        x += t;
        lscan[tid] = x;
        __syncthreads();
    }
    int excl = x - v;                          // exclusive scan within bucket
    int node = kb * 256 + tid;
    if (node < n) {
        rowptr[node] = base + excl;
        dinv[node]   = rsqrtf((float)(v + 1)); // +1 self-loop
    }
    cursor[tid] = base + excl;
    if (kb == NBUCK - 1 && tid == 0) rowptr[n] = E;
    __syncthreads();
    for (int i = tid; i < cnt; i += 256) {            // pass B: place src
        uint_t u = bkt[base + i];                     // L2 hit (just touched)
        int pos = atomicAdd(&cursor[(u >> 16) & 255], 1);   // LDS atomic
        csr[pos] = (ushort_t)(u & 0xffffu);    // 2B scatter, block-local region
    }
}

// ---- W1 -> bf16, pre-swizzled into MFMA B-fragment order -------------------
__global__ void convert_w1_kernel(const float* __restrict__ W1, ushort_t* __restrict__ W1s) {
    int t = blockIdx.x * blockDim.x + threadIdx.x;   // 2048 triples
    if (t >= 4 * 8 * 64) return;
    int lane = t & 63;
    int kk   = (t >> 6) & 7;
    int nt   = t >> 9;
    int col  = nt * 16 + (lane & 15);
    int k0   = kk * 32 + (lane >> 4) * 8;
    ushort_t v[8];
    #pragma unroll
    for (int j = 0; j < 8; ++j) v[j] = f2bf(W1[(size_t)(k0 + j) * HID + col]);
    uint4 p;
    p.x = (uint_t)v[0] | ((uint_t)v[1] << 16);
    p.y = (uint_t)v[2] | ((uint_t)v[3] << 16);
    p.z = (uint_t)v[4] | ((uint_t)v[5] << 16);
    p.w = (uint_t)v[6] | ((uint_t)v[7] << 16);
    *(uint4*)(W1s + (size_t)t * 8) = p;
}

// ------- layer 1 GEMM on MFMA: xws = bf16((x @ W1) * dinv[node]) ------------
__global__ void gemm1_mfma_kernel(const float* __restrict__ x,
                                  const ushort_t* __restrict__ W1s,
                                  const float* __restrict__ dinv,
                                  ushort_t* __restrict__ xws, int n) {
    __shared__ ushort_t xs[16 * XS_STRIDE];           // 8448 B bf16 x-tile
    int node0 = blockIdx.x * 16;
    int tid = threadIdx.x;
    for (int i = tid; i < 16 * 64; i += 256) {        // stage x tile -> bf16 LDS
        int r  = i >> 6;
        int c4 = (i & 63) << 2;
        int node = node0 + r;
        float4 v = (node < n) ? *(const float4*)(x + (size_t)node * F_IN + c4)
                              : make_float4(0.f, 0.f, 0.f, 0.f);
        ushort4 b;
        b.x = f2bf(v.x); b.y = f2bf(v.y); b.z = f2bf(v.z); b.w = f2bf(v.w);
        *(ushort4*)(&xs[r * XS_STRIDE + c4]) = b;     // 8B-aligned ds_write_b64
    }
    __syncthreads();
    int wave = tid >> 6;                              // N-tile index 0..3
    int lane = tid & 63;
    int m    = lane & 15;
    int q    = lane >> 4;
    f32x4 acc = {0.f, 0.f, 0.f, 0.f};
    #pragma unroll
    for (int kk = 0; kk < 8; ++kk) {                  // K = 8 x 32
        bf16x8 a = *(const bf16x8*)(&xs[m * XS_STRIDE + kk * 32 + q * 8]);
        bf16x8 b = *(const bf16x8*)(W1s + (((size_t)wave * 8 + kk) * 64 + lane) * 8);
        acc = __builtin_amdgcn_mfma_f32_16x16x32_bf16(a, b, acc, 0, 0, 0);
    }
    int ch = wave * 16 + m;                           // C/D: col=lane&15, row=q*4+r
    #pragma unroll
    for (int r = 0; r < 4; ++r) {
        int node = node0 + q * 4 + r;
        if (node < n)
            xws[(size_t)node * HID + ch] = f2bf(acc[r] * dinv[node]);
    }
}

// ---- fused: gather1 (h = relu(dinv*(sum)+b1)) + gemm2 (hws = h@W2 * dinv) --
// one wave per node. csr indices loaded 64-at-a-time by lanes + __shfl extract;
// always-full batches of 32 (uniform predicate, no serial tails); W2 in LDS.
__global__ void __launch_bounds__(256, 2)
gather1_gemm2_kernel(const int* __restrict__ rowptr,
                     const ushort_t* __restrict__ csr,
                     const ushort_t* __restrict__ xws,
                     const float* __restrict__ dinv,
                     const float* __restrict__ b1,
                     const float* __restrict__ W2,
                     ushort_t* __restrict__ hws, int n) {
    __shared__ float hbuf[4][72];
    __shared__ float w2s[HID * CLS];                  // 10240 B
    int tid  = threadIdx.x;
    int wave = tid >> 6;
    int c    = tid & 63;
    // stage W2 -> LDS (float4), overlapped with gather; barrier below covers it
    for (int i = tid; i < HID * CLS / 4; i += 256)
        *(float4*)(&w2s[i * 4]) = *(const float4*)(W2 + i * 4);
    int wv   = (blockIdx.x * blockDim.x + tid) >> 6;
    bool active = wv < n;
    int beg = 0, endp = 0;
    float acc = 0.f, di = 0.f;
    if (active) {
        beg = rowptr[wv]; endp = rowptr[wv + 1];
        di  = dinv[wv];
        acc = bf2f(xws[(size_t)wv * HID + c]);        // self-loop term
    }
    for (int ch = beg; ch < endp; ch += 64) {         // 64-index chunks
        int m = endp - ch; if (m > 64) m = 64;
        int iv = 0;
        if (c < m) iv = (int)csr[ch + c];             // one coalesced index load
        for (int b = 0; b < m; b += 32) {             // full batches of 32
            float vv[32];
            #pragma unroll
            for (int t = 0; t < 32; ++t) {
                int q = b + t;
                float v = 0.f;
                if (q < m) {                          // wave-uniform predicate
                    int s = __shfl(iv, q);
                    v = bf2f(xws[(size_t)s * HID + c]);
                }
                vv[t] = v;
            }
            #pragma unroll
            for (int o = 16; o > 0; o >>= 1) {
                #pragma unroll
                for (int t = 0; t < 16; ++t)
                    if (t < o) vv[t] += vv[t + o];
            }
            acc += vv[0];
        }
    }
    float hv = active ? fmaxf(acc * di + b1[c], 0.f) : 0.f;
    hbuf[wave][c] = hv;
    __syncthreads();                                  // covers w2s + hbuf
    if (active && c < CLS) {
        float o = 0.f;
        const float* hr = hbuf[wave];
        #pragma unroll 16
        for (int k = 0; k < HID; ++k) o += hr[k] * w2s[k * CLS + c];
        hws[(size_t)wv * CLS + c] = f2bf(o * di);
    }
}

// ---------- layer 2 gather fused with finalize ------------------------------
__global__ void __launch_bounds__(256, 2)
gather2_fin_kernel(const int* __restrict__ rowptr,
                   const ushort_t* __restrict__ csr,
                   const ushort_t* __restrict__ hws,
                   const float* __restrict__ dinv,
                   const float* __restrict__ b2,
                   float* __restrict__ xout, float* __restrict__ lsm,
                   float* __restrict__ sm, ushort_t* __restrict__ xoutb,
                   float* __restrict__ rnorm, int n) {
    int wv = (blockIdx.x * blockDim.x + threadIdx.x) >> 6;
    int c  = threadIdx.x & 63;
    if (wv >= n) return;
    int beg = rowptr[wv], endp = rowptr[wv + 1];
    bool act = c < CLS;
    float acc = 0.f;
    if (act) acc = bf2f(hws[(size_t)wv * CLS + c]);   // self-loop term
    for (int ch = beg; ch < endp; ch += 64) {         // 64-index chunks
        int m = endp - ch; if (m > 64) m = 64;
        int iv = 0;
        if (c < m) iv = (int)csr[ch + c];             // one coalesced index load
        for (int b = 0; b < m; b += 32) {             // full batches of 32
            float vv[32];
            #pragma unroll
            for (int t = 0; t < 32; ++t) {
                int q = b + t;
                float v = 0.f;
                if (q < m) {                          // wave-uniform predicate
                    int s = __shfl(iv, q);
                    if (act) v = bf2f(hws[(size_t)s * CLS + c]);
                }
                vv[t] = v;
            }
            #pragma unroll
            for (int o = 16; o > 0; o >>= 1) {
                #pragma unroll
                for (int t = 0; t < 16; ++t)
                    if (t < o) vv[t] += vv[t + o];
            }
            acc += vv[0];
        }
    }
    float raw = 0.f;
    if (act) raw = acc * dinv[wv] + b2[c];
    float m = act ? raw : -3.0e38f;
    #pragma unroll
    for (int o = 32; o > 0; o >>= 1) m = fmaxf(m, __shfl_xor(m, o));
    float ex = act ? __expf(raw - m) : 0.f;
    float ssum = ex;
    #pragma unroll
    for (int o = 32; o > 0; o >>= 1) ssum += __shfl_xor(ssum, o);
    float sq = act ? raw * raw : 0.f;
    #pragma unroll
    for (int o = 32; o > 0; o >>= 1) sq += __shfl_xor(sq, o);
    size_t base = (size_t)wv * CLS + c;
    if (act) {
        xout[base]  = raw;
        float lse = m + __logf(ssum);
        lsm[base]   = raw - lse;
        sm[base]    = ex / ssum;
        xoutb[base] = f2bf(raw);
    }
    if (c == 0) rnorm[wv] = 1.0f / fmaxf(sqrtf(sq), EPS);
}

// ------------- per-edge cosine dissimilarity + gnn_edge ---------------------
__global__ void edge_kernel(const uint_t* __restrict__ pair,
                            const float* __restrict__ ew, const ushort_t* __restrict__ xoutb,
                            const float* __restrict__ rnorm,
                            float* __restrict__ cos_out, float* __restrict__ gnn_out, int E) {
    int e = blockIdx.x * blockDim.x + threadIdx.x;
    if (e >= E) return;
    uint_t u = pair[e];
    int s = (int)(u & 0xffffu);
    int d = (int)(u >> 16);
    const uint4* a4 = (const uint4*)(xoutb + (size_t)s * CLS);   // rows are 80B = 5*16B
    const uint4* b4 = (const uint4*)(xoutb + (size_t)d * CLS);
    uint4 a0 = a4[0], a1 = a4[1], a2 = a4[2], a3 = a4[3], a4v = a4[4];
    uint4 b0 = b4[0], b1 = b4[1], b2 = b4[2], b3 = b4[3], b4v = b4[4];
    float rs = rnorm[s], rd = rnorm[d];
    float dot = dot_u4(a0, b0) + dot_u4(a1, b1) + dot_u4(a2, b2)
              + dot_u4(a3, b3) + dot_u4(a4v, b4v);
    cos_out[e] = 1.0f - dot * rs * rd;
    gnn_out[e] = (ew[e] > 0.5f) ? 1.0f : -1.0f;
}

// ---------------------------------------------------------------------------
extern "C" void kernel_launch(void* const* d_in, const int* in_sizes, int n_in,
                              void* d_out, int out_size, void* d_ws, size_t ws_size,
                              hipStream_t stream) {
    const float* x   = (const float*)d_in[0];
    const void*  ei  = d_in[1];
    const float* ew  = (const float*)d_in[2];
    const float* W1  = (const float*)d_in[3];
    const float* b1  = (const float*)d_in[4];
    const float* W2  = (const float*)d_in[5];
    const float* b2  = (const float*)d_in[6];

    const int n = in_sizes[0] / F_IN;        // 50000
    const int E = in_sizes[2];               // 1600000

    // output segments (return order)
    float* lsm  = (float*)d_out;                                   // [n*CLS]
    float* xout = lsm + (size_t)n * CLS;                           // [n*CLS]
    float* cosO = xout + (size_t)n * CLS;                          // [E]
    float* gnnO = cosO + E;                                        // [E]
    float* smO  = gnnO + E;                                        // [n*CLS]

    // workspace layout (256B aligned)
    char* w = (char*)d_ws;
    auto alloc = [&](size_t bytes) {
        char* p = w;
        w += (bytes + 255) & ~(size_t)255;
        return p;
    };
    const int NBLK  = (E + EPB - 1) / EPB;   // 196 hist/scatter blocks
    const int NBUCK = (n + 255) / 256;       // 196 buckets (dst>>8)

    uint_t*   pair   = (uint_t*)  alloc((size_t)E * 4);
    uint_t*   bkt    = (uint_t*)  alloc((size_t)E * 4);
    ushort_t* csr16  = (ushort_t*)alloc((size_t)E * 2);
    int*      ghist  = (int*)     alloc((size_t)NBLK * 256 * 4);
    int*      btot   = (int*)     alloc(256 * 4);
    int*      bbase  = (int*)     alloc(257 * 4);
    int*      rowptr = (int*)     alloc(((size_t)n + 1) * 4);
    float*    dinv   = (float*)   alloc((size_t)n * 4);
    ushort_t* xws    = (ushort_t*)alloc((size_t)n * HID * 2);
    ushort_t* hws    = (ushort_t*)alloc((size_t)n * CLS * 2);
    ushort_t* xoutb  = (ushort_t*)alloc((size_t)n * CLS * 2);
    float*    rnorm  = (float*)   alloc((size_t)n * 4);
    ushort_t* W1s    = (ushort_t*)alloc((size_t)4 * 8 * 64 * 8 * 2);   // 32 KB
    int*      flag   = (int*)     alloc(64);

    detect_kernel<<<1, 64, 0, stream>>>((const int*)ei, flag);
    convert_w1_kernel<<<8, 256, 0, stream>>>(W1, W1s);
    build_hist_kernel<<<NBLK, 256, 0, stream>>>(ei, flag, pair, ghist, E);
    scan_cols_kernel<<<256, 64, 0, stream>>>(ghist, btot, NBLK);
    scan_base_kernel<<<1, 256, 0, stream>>>(btot, bbase);
    scatter_buckets_kernel<<<NBLK, 256, 0, stream>>>(pair, ghist, bbase, bkt, E);
    bucket_csr_kernel<<<NBUCK, 256, 0, stream>>>(bkt, bbase, csr16, rowptr, dinv, n, E, NBUCK);
    gemm1_mfma_kernel<<<(n + 15) / 16, 256, 0, stream>>>(x, W1s, dinv, xws, n);
    gather1_gemm2_kernel<<<((size_t)n * 64 + 255) / 256, 256, 0, stream>>>(rowptr, csr16, xws, dinv,
                                                                           b1, W2, hws, n);
    gather2_fin_kernel<<<((size_t)n * 64 + 255) / 256, 256, 0, stream>>>(rowptr, csr16, hws, dinv, b2,
                                                                         xout, lsm, smO, xoutb, rnorm, n);
    edge_kernel<<<(E + 255) / 256, 256, 0, stream>>>(pair, ew, xoutb, rnorm, cosO, gnnO, E);
}

// Round 7
// 308.688 us; speedup vs baseline: 1.3635x; 1.3635x over previous
//
#include <hip/hip_runtime.h>
#include <hip/hip_bf16.h>

#define F_IN 256
#define HID  64
#define CLS  40
#define EPS  1e-8f
#define XS_STRIDE 264   // halfwords per LDS x-tile row: 2-way max bank aliasing (free)
#define EPB  8192       // edges per block in hist/scatter passes (256 thr x 32)

typedef unsigned short ushort_t;
typedef unsigned int   uint_t;
typedef __attribute__((ext_vector_type(8))) short bf16x8;
typedef __attribute__((ext_vector_type(4))) float f32x4;

__device__ __forceinline__ float bf2f(ushort_t u) {
    union { uint_t i; float f; } v; v.i = ((uint_t)u) << 16; return v.f;
}
__device__ __forceinline__ ushort_t f2bf(float f) {
    union { float f; uint_t i; } v; v.f = f;
    uint_t r = v.i + 0x7fff + ((v.i >> 16) & 1);          // RNE
    return (ushort_t)(r >> 16);
}
__device__ __forceinline__ float blo(uint_t p) {
    union { uint_t i; float f; } v; v.i = p << 16; return v.f;
}
__device__ __forceinline__ float bhi(uint_t p) {
    union { uint_t i; float f; } v; v.i = p & 0xffff0000u; return v.f;
}
__device__ __forceinline__ float dot_u4(uint4 a, uint4 b) {
    return blo(a.x) * blo(b.x) + bhi(a.x) * bhi(b.x)
         + blo(a.y) * blo(b.y) + bhi(a.y) * bhi(b.y)
         + blo(a.z) * blo(b.z) + bhi(a.z) * bhi(b.z)
         + blo(a.w) * blo(b.w) + bhi(a.w) * bhi(b.w);
}

// -------------------- dtype detection (int64 vs int32 edge_index) -----------
__global__ void detect_kernel(const int* __restrict__ raw, int* __restrict__ flag) {
    int c = threadIdx.x;                  // one wave
    int w = raw[2 * c + 1];               // odd int32 words
    unsigned long long b = __ballot(w != 0);
    if (c == 0) *flag = (b == 0ULL) ? 1 : 0;   // all zero -> int64 layout
}

// ---- pass 1: pair packing + per-block bucket histogram (dst>>8) ------------
__global__ void build_hist_kernel(const void* __restrict__ raw, const int* __restrict__ flag,
                                  uint_t* __restrict__ pair, int* __restrict__ ghist, int E) {
    __shared__ int lhist[256];
    int tid = threadIdx.x;
    lhist[tid] = 0;
    __syncthreads();
    int base = blockIdx.x * EPB;
    if (*flag) {
        const long long* r = (const long long*)raw;
        for (int it = 0; it < EPB / 1024; ++it) {        // 4 edges/thread/iter
            int e = base + (it * 256 + tid) * 4;
            if (e + 4 <= E) {
                ulonglong2 a0 = *(const ulonglong2*)(r + e);
                ulonglong2 a1 = *(const ulonglong2*)(r + e + 2);
                ulonglong2 b0 = *(const ulonglong2*)(r + E + e);
                ulonglong2 b1 = *(const ulonglong2*)(r + E + e + 2);
                uint_t d0 = (uint_t)b0.x, d1 = (uint_t)b0.y;
                uint_t d2 = (uint_t)b1.x, d3 = (uint_t)b1.y;
                uint4 p;
                p.x = (d0 << 16) | (uint_t)a0.x;
                p.y = (d1 << 16) | (uint_t)a0.y;
                p.z = (d2 << 16) | (uint_t)a1.x;
                p.w = (d3 << 16) | (uint_t)a1.y;
                *(uint4*)(pair + e) = p;
                atomicAdd(&lhist[d0 >> 8], 1);
                atomicAdd(&lhist[d1 >> 8], 1);
                atomicAdd(&lhist[d2 >> 8], 1);
                atomicAdd(&lhist[d3 >> 8], 1);
            } else {
                for (int k = 0; k < 4; ++k) {
                    int ee = e + k;
                    if (ee < E) {
                        uint_t s = (uint_t)r[ee];
                        uint_t d = (uint_t)r[E + ee];
                        pair[ee] = (d << 16) | s;
                        atomicAdd(&lhist[d >> 8], 1);
                    }
                }
            }
        }
    } else {
        const int* r = (const int*)raw;
        for (int it = 0; it < EPB / 1024; ++it) {        // 4 edges/thread/iter
            int e = base + (it * 256 + tid) * 4;
            if (e + 4 <= E) {
                int4 a = *(const int4*)(r + e);
                int4 b = *(const int4*)(r + E + e);
                uint_t d0 = (uint_t)b.x, d1 = (uint_t)b.y;
                uint_t d2 = (uint_t)b.z, d3 = (uint_t)b.w;
                uint4 p;
                p.x = (d0 << 16) | (uint_t)a.x;
                p.y = (d1 << 16) | (uint_t)a.y;
                p.z = (d2 << 16) | (uint_t)a.z;
                p.w = (d3 << 16) | (uint_t)a.w;
                *(uint4*)(pair + e) = p;
                atomicAdd(&lhist[d0 >> 8], 1);
                atomicAdd(&lhist[d1 >> 8], 1);
                atomicAdd(&lhist[d2 >> 8], 1);
                atomicAdd(&lhist[d3 >> 8], 1);
            } else {
                for (int k = 0; k < 4; ++k) {
                    int ee = e + k;
                    if (ee < E) {
                        uint_t s = (uint_t)r[ee];
                        uint_t d = (uint_t)r[E + ee];
                        pair[ee] = (d << 16) | s;
                        atomicAdd(&lhist[d >> 8], 1);
                    }
                }
            }
        }
    }
    __syncthreads();
    ghist[blockIdx.x * 256 + tid] = lhist[tid];
}

// ---- pass 2a: PARALLEL column scan — one wave per bucket -------------------
__global__ void scan_cols_kernel(int* __restrict__ ghist, int* __restrict__ btot,
                                 int NBLK) {
    int k    = blockIdx.x;                 // bucket 0..255
    int lane = threadIdx.x;                // 0..63
    int carry = 0;
    for (int b0 = 0; b0 < NBLK; b0 += 64) {
        int b = b0 + lane;
        int v = (b < NBLK) ? ghist[b * 256 + k] : 0;
        int x = v;
        #pragma unroll
        for (int o = 1; o < 64; o <<= 1) {
            int t = __shfl_up(x, o);
            if (lane >= o) x += t;
        }
        if (b < NBLK) ghist[b * 256 + k] = carry + x - v;   // exclusive offset
        carry += __shfl(x, 63);            // batch total
    }
    if (lane == 0) btot[k] = carry;        // bucket total
}

// ---- pass 2b (1 block): exclusive scan of bucket totals -> bucket bases ----
__global__ void scan_base_kernel(const int* __restrict__ btot, int* __restrict__ bbase) {
    __shared__ int s[256];
    int k = threadIdx.x;
    int v = btot[k];
    int x = v;
    s[k] = x;
    __syncthreads();
    #pragma unroll
    for (int o = 1; o < 256; o <<= 1) {
        int t = (k >= o) ? s[k - o] : 0;
        __syncthreads();
        x += t;
        s[k] = x;
        __syncthreads();
    }
    bbase[k] = x - v;                      // exclusive bucket base
    if (k == 255) bbase[256] = x;          // == E
}

// ---- pass 3: scatter edges into bucket regions (LDS cursors only) ----------
__global__ void scatter_buckets_kernel(const uint_t* __restrict__ pair,
                                       const int* __restrict__ ghist,
                                       const int* __restrict__ bbase,
                                       uint_t* __restrict__ bkt, int E) {
    __shared__ int cursor[256];
    int tid = threadIdx.x;
    cursor[tid] = ghist[blockIdx.x * 256 + tid] + bbase[tid];
    __syncthreads();
    int base = blockIdx.x * EPB;
    for (int it = 0; it < EPB / 256; ++it) {
        int e = base + it * 256 + tid;
        if (e < E) {
            uint_t u = pair[e];
            int pos = atomicAdd(&cursor[u >> 24], 1);   // LDS atomic, returns rank
            bkt[pos] = u;
        }
    }
}

// ---- pass 4: one block per bucket -> deg/rowptr/dinv + sorted csr16 --------
__global__ void bucket_csr_kernel(const uint_t* __restrict__ bkt,
                                  const int* __restrict__ bbase,
                                  ushort_t* __restrict__ csr, int* __restrict__ rowptr,
                                  float* __restrict__ dinv, int n, int E, int NBUCK) {
    __shared__ int lhist[256];
    __shared__ int lscan[256];
    __shared__ int cursor[256];
    int tid = threadIdx.x;
    int kb  = blockIdx.x;
    int base = bbase[kb];
    int cnt  = bbase[kb + 1] - base;
    lhist[tid] = 0;
    __syncthreads();
    for (int i = tid; i < cnt; i += 256) {            // pass A: exact degrees
        uint_t u = bkt[base + i];
        atomicAdd(&lhist[(u >> 16) & 255], 1);
    }
    __syncthreads();
    int v = lhist[tid];                        // degree of node kb*256+tid (no self-loop)
    int x = v;
    lscan[tid] = x;
    __syncthreads();
    #pragma unroll
    for (int o = 1; o < 256; o <<= 1) {
        int t = (tid >= o) ? lscan[tid - o] : 0;
        __syncthreads();
        x += t;
        lscan[tid] = x;
        __syncthreads();
    }
    int excl = x - v;                          // exclusive scan within bucket
    int node = kb * 256 + tid;
    if (node < n) {
        rowptr[node] = base + excl;
        dinv[node]   = rsqrtf((float)(v + 1)); // +1 self-loop
    }
    cursor[tid] = base + excl;
    if (kb == NBUCK - 1 && tid == 0) rowptr[n] = E;
    __syncthreads();
    for (int i = tid; i < cnt; i += 256) {            // pass B: place src
        uint_t u = bkt[base + i];                     // L2 hit (just touched)
        int pos = atomicAdd(&cursor[(u >> 16) & 255], 1);   // LDS atomic
        csr[pos] = (ushort_t)(u & 0xffffu);    // 2B scatter, block-local region
    }
}

// ---- W1 -> bf16, pre-swizzled into MFMA B-fragment order -------------------
__global__ void convert_w1_kernel(const float* __restrict__ W1, ushort_t* __restrict__ W1s) {
    int t = blockIdx.x * blockDim.x + threadIdx.x;   // 2048 triples
    if (t >= 4 * 8 * 64) return;
    int lane = t & 63;
    int kk   = (t >> 6) & 7;
    int nt   = t >> 9;
    int col  = nt * 16 + (lane & 15);
    int k0   = kk * 32 + (lane >> 4) * 8;
    ushort_t v[8];
    #pragma unroll
    for (int j = 0; j < 8; ++j) v[j] = f2bf(W1[(size_t)(k0 + j) * HID + col]);
    uint4 p;
    p.x = (uint_t)v[0] | ((uint_t)v[1] << 16);
    p.y = (uint_t)v[2] | ((uint_t)v[3] << 16);
    p.z = (uint_t)v[4] | ((uint_t)v[5] << 16);
    p.w = (uint_t)v[6] | ((uint_t)v[7] << 16);
    *(uint4*)(W1s + (size_t)t * 8) = p;
}

// ------- layer 1 GEMM on MFMA: xws = bf16((x @ W1) * dinv[node]) ------------
__global__ void gemm1_mfma_kernel(const float* __restrict__ x,
                                  const ushort_t* __restrict__ W1s,
                                  const float* __restrict__ dinv,
                                  ushort_t* __restrict__ xws, int n) {
    __shared__ ushort_t xs[16 * XS_STRIDE];           // 8448 B bf16 x-tile
    int node0 = blockIdx.x * 16;
    int tid = threadIdx.x;
    for (int i = tid; i < 16 * 64; i += 256) {        // stage x tile -> bf16 LDS
        int r  = i >> 6;
        int c4 = (i & 63) << 2;
        int node = node0 + r;
        float4 v = (node < n) ? *(const float4*)(x + (size_t)node * F_IN + c4)
                              : make_float4(0.f, 0.f, 0.f, 0.f);
        ushort4 b;
        b.x = f2bf(v.x); b.y = f2bf(v.y); b.z = f2bf(v.z); b.w = f2bf(v.w);
        *(ushort4*)(&xs[r * XS_STRIDE + c4]) = b;     // 8B-aligned ds_write_b64
    }
    __syncthreads();
    int wave = tid >> 6;                              // N-tile index 0..3
    int lane = tid & 63;
    int m    = lane & 15;
    int q    = lane >> 4;
    f32x4 acc = {0.f, 0.f, 0.f, 0.f};
    #pragma unroll
    for (int kk = 0; kk < 8; ++kk) {                  // K = 8 x 32
        bf16x8 a = *(const bf16x8*)(&xs[m * XS_STRIDE + kk * 32 + q * 8]);
        bf16x8 b = *(const bf16x8*)(W1s + (((size_t)wave * 8 + kk) * 64 + lane) * 8);
        acc = __builtin_amdgcn_mfma_f32_16x16x32_bf16(a, b, acc, 0, 0, 0);
    }
    int ch = wave * 16 + m;                           // C/D: col=lane&15, row=q*4+r
    #pragma unroll
    for (int r = 0; r < 4; ++r) {
        int node = node0 + q * 4 + r;
        if (node < n)
            xws[(size_t)node * HID + ch] = f2bf(acc[r] * dinv[node]);
    }
}

// ---- fused: gather1 (h = relu(dinv*(sum)+b1)) + gemm2 (hws = h@W2 * dinv) --
// one wave per node; 8 lane-groups x 16B = one dwordx4 instruction fetches
// 8 edge-rows (1KB). Indices via csr[ch + (l>>3)] (one 16B line, no shfl).
// acc8[8] per lane; cross-group xor-reduce (^8,^16,^32) at the end.
__global__ void gather1_gemm2_kernel(const int* __restrict__ rowptr,
                                     const ushort_t* __restrict__ csr,
                                     const ushort_t* __restrict__ xws,
                                     const float* __restrict__ dinv,
                                     const float* __restrict__ b1,
                                     const float* __restrict__ W2,
                                     ushort_t* __restrict__ hws, int n) {
    __shared__ float hbuf[4][72];
    __shared__ float w2s[HID * CLS];                  // 10240 B
    int tid  = threadIdx.x;
    int wave = tid >> 6;
    int l    = tid & 63;
    int g    = l >> 3;                                // row-group 0..7
    int lc   = l & 7;                                 // channel-group (8 ch each)
    for (int i = tid; i < HID * CLS / 4; i += 256)
        *(float4*)(&w2s[i * 4]) = *(const float4*)(W2 + i * 4);
    int wv = (blockIdx.x * blockDim.x + tid) >> 6;
    bool active = wv < n;
    int beg = 0, endp = 0;
    float di = 0.f;
    float acc8[8];
    #pragma unroll
    for (int j = 0; j < 8; ++j) acc8[j] = 0.f;
    if (active) {
        beg = rowptr[wv]; endp = rowptr[wv + 1];
        di  = dinv[wv];
        if (l < 8) {                                  // self-loop: group 0 only
            uint4 sv = *(const uint4*)(xws + (size_t)wv * HID + lc * 8);
            acc8[0] = blo(sv.x); acc8[1] = bhi(sv.x);
            acc8[2] = blo(sv.y); acc8[3] = bhi(sv.y);
            acc8[4] = blo(sv.z); acc8[5] = bhi(sv.z);
            acc8[6] = blo(sv.w); acc8[7] = bhi(sv.w);
        }
    }
    for (int ch = beg; ch < endp; ch += 32) {         // 32 edges per iteration
        #pragma unroll
        for (int k = 0; k < 4; ++k) {                 // 4 independent 8-row loads
            int e = ch + k * 8 + g;
            bool val = e < endp;
            int ec = val ? e : (endp - 1);            // clamp, mask value below
            int s = (int)csr[ec];                     // 64 lanes -> one 16B line
            uint4 p = *(const uint4*)(xws + (size_t)s * HID + lc * 8);
            if (!val) { p.x = 0u; p.y = 0u; p.z = 0u; p.w = 0u; }
            acc8[0] += blo(p.x); acc8[1] += bhi(p.x);
            acc8[2] += blo(p.y); acc8[3] += bhi(p.y);
            acc8[4] += blo(p.z); acc8[5] += bhi(p.z);
            acc8[6] += blo(p.w); acc8[7] += bhi(p.w);
        }
    }
    #pragma unroll
    for (int j = 0; j < 8; ++j) {                     // sum the 8 row-groups
        float v = acc8[j];
        v += __shfl_xor(v, 8);
        v += __shfl_xor(v, 16);
        v += __shfl_xor(v, 32);
        acc8[j] = v;
    }
    if (active && l < 8) {                            // group 0 writes h row
        #pragma unroll
        for (int j = 0; j < 8; ++j)
            hbuf[wave][lc * 8 + j] = fmaxf(acc8[j] * di + b1[lc * 8 + j], 0.f);
    }
    __syncthreads();                                  // covers w2s + hbuf
    if (active) {
        if (l < CLS) {
            float o = 0.f;
            const float* hr = hbuf[wave];
            #pragma unroll 16
            for (int k = 0; k < HID; ++k) o += hr[k] * w2s[k * CLS + l];
            hws[(size_t)wv * HID + l] = f2bf(o * di);
        } else {
            hws[(size_t)wv * HID + l] = 0;            // zero-pad ch 40..63
        }
    }
}

// ---------- layer 2 gather fused with finalize ------------------------------
// hws rows padded to 64 bf16 (128B) -> identical 8x8 load structure.
__global__ void gather2_fin_kernel(const int* __restrict__ rowptr,
                                   const ushort_t* __restrict__ csr,
                                   const ushort_t* __restrict__ hws,
                                   const float* __restrict__ dinv,
                                   const float* __restrict__ b2,
                                   float* __restrict__ xout, float* __restrict__ lsm,
                                   float* __restrict__ sm, ushort_t* __restrict__ xoutb,
                                   float* __restrict__ rnorm, int n) {
    int tid = threadIdx.x;
    int wv  = (blockIdx.x * blockDim.x + tid) >> 6;
    if (wv >= n) return;
    int l  = tid & 63;
    int g  = l >> 3;
    int lc = l & 7;                                   // channels lc*8..lc*8+7
    int beg = rowptr[wv], endp = rowptr[wv + 1];
    float di = dinv[wv];
    float acc8[8];
    #pragma unroll
    for (int j = 0; j < 8; ++j) acc8[j] = 0.f;
    if (l < 8) {                                      // self-loop term
        uint4 sv = *(const uint4*)(hws + (size_t)wv * HID + lc * 8);
        acc8[0] = blo(sv.x); acc8[1] = bhi(sv.x);
        acc8[2] = blo(sv.y); acc8[3] = bhi(sv.y);
        acc8[4] = blo(sv.z); acc8[5] = bhi(sv.z);
        acc8[6] = blo(sv.w); acc8[7] = bhi(sv.w);
    }
    for (int ch = beg; ch < endp; ch += 32) {
        #pragma unroll
        for (int k = 0; k < 4; ++k) {
            int e = ch + k * 8 + g;
            bool val = e < endp;
            int ec = val ? e : (endp - 1);
            int s = (int)csr[ec];
            uint4 p = *(const uint4*)(hws + (size_t)s * HID + lc * 8);
            if (!val) { p.x = 0u; p.y = 0u; p.z = 0u; p.w = 0u; }
            acc8[0] += blo(p.x); acc8[1] += bhi(p.x);
            acc8[2] += blo(p.y); acc8[3] += bhi(p.y);
            acc8[4] += blo(p.z); acc8[5] += bhi(p.z);
            acc8[6] += blo(p.w); acc8[7] += bhi(p.w);
        }
    }
    #pragma unroll
    for (int j = 0; j < 8; ++j) {
        float v = acc8[j];
        v += __shfl_xor(v, 8);
        v += __shfl_xor(v, 16);
        v += __shfl_xor(v, 32);
        acc8[j] = v;
    }
    bool cgv = lc < 5;                                // 40 = 5 groups x 8 ch
    float raw[8];
    if (cgv) {
        #pragma unroll
        for (int j = 0; j < 8; ++j) raw[j] = acc8[j] * di + b2[lc * 8 + j];
    } else {
        #pragma unroll
        for (int j = 0; j < 8; ++j) raw[j] = 0.f;
    }
    float mx = -3.0e38f;
    if (cgv) {
        #pragma unroll
        for (int j = 0; j < 8; ++j) mx = fmaxf(mx, raw[j]);
    }
    mx = fmaxf(mx, __shfl_xor(mx, 1));
    mx = fmaxf(mx, __shfl_xor(mx, 2));
    mx = fmaxf(mx, __shfl_xor(mx, 4));
    float ex[8];
    float ls = 0.f;
    if (cgv) {
        #pragma unroll
        for (int j = 0; j < 8; ++j) { ex[j] = __expf(raw[j] - mx); ls += ex[j]; }
    } else {
        #pragma unroll
        for (int j = 0; j < 8; ++j) ex[j] = 0.f;
    }
    ls += __shfl_xor(ls, 1);
    ls += __shfl_xor(ls, 2);
    ls += __shfl_xor(ls, 4);
    float sq = 0.f;
    if (cgv) {
        #pragma unroll
        for (int j = 0; j < 8; ++j) sq += raw[j] * raw[j];
    }
    sq += __shfl_xor(sq, 1);
    sq += __shfl_xor(sq, 2);
    sq += __shfl_xor(sq, 4);
    if (l < 5) {                                      // lanes 0..4 write row
        size_t fb = (size_t)wv * CLS + l * 8;
        *(float4*)(xout + fb)     = make_float4(raw[0], raw[1], raw[2], raw[3]);
        *(float4*)(xout + fb + 4) = make_float4(raw[4], raw[5], raw[6], raw[7]);
        float lse = mx + __logf(ls);
        *(float4*)(lsm + fb)     = make_float4(raw[0] - lse, raw[1] - lse, raw[2] - lse, raw[3] - lse);
        *(float4*)(lsm + fb + 4) = make_float4(raw[4] - lse, raw[5] - lse, raw[6] - lse, raw[7] - lse);
        float inv = 1.0f / ls;
        *(float4*)(sm + fb)     = make_float4(ex[0] * inv, ex[1] * inv, ex[2] * inv, ex[3] * inv);
        *(float4*)(sm + fb + 4) = make_float4(ex[4] * inv, ex[5] * inv, ex[6] * inv, ex[7] * inv);
        uint4 pb;
        pb.x = (uint_t)f2bf(raw[0]) | ((uint_t)f2bf(raw[1]) << 16);
        pb.y = (uint_t)f2bf(raw[2]) | ((uint_t)f2bf(raw[3]) << 16);
        pb.z = (uint_t)f2bf(raw[4]) | ((uint_t)f2bf(raw[5]) << 16);
        pb.w = (uint_t)f2bf(raw[6]) | ((uint_t)f2bf(raw[7]) << 16);
        *(uint4*)(xoutb + fb) = pb;                   // byte off = wv*80+l*16, 16B-aligned
    }
    if (l == 0) rnorm[wv] = 1.0f / fmaxf(sqrtf(sq), EPS);
}

// ------------- per-edge cosine dissimilarity + gnn_edge ---------------------
__global__ void edge_kernel(const uint_t* __restrict__ pair,
                            const float* __restrict__ ew, const ushort_t* __restrict__ xoutb,
                            const float* __restrict__ rnorm,
                            float* __restrict__ cos_out, float* __restrict__ gnn_out, int E) {
    int e = blockIdx.x * blockDim.x + threadIdx.x;
    if (e >= E) return;
    uint_t u = pair[e];
    int s = (int)(u & 0xffffu);
    int d = (int)(u >> 16);
    const uint4* a4 = (const uint4*)(xoutb + (size_t)s * CLS);   // rows are 80B = 5*16B
    const uint4* b4 = (const uint4*)(xoutb + (size_t)d * CLS);
    uint4 a0 = a4[0], a1 = a4[1], a2 = a4[2], a3 = a4[3], a4v = a4[4];
    uint4 b0 = b4[0], b1 = b4[1], b2 = b4[2], b3 = b4[3], b4v = b4[4];
    float rs = rnorm[s], rd = rnorm[d];
    float dot = dot_u4(a0, b0) + dot_u4(a1, b1) + dot_u4(a2, b2)
              + dot_u4(a3, b3) + dot_u4(a4v, b4v);
    cos_out[e] = 1.0f - dot * rs * rd;
    gnn_out[e] = (ew[e] > 0.5f) ? 1.0f : -1.0f;
}

// ---------------------------------------------------------------------------
extern "C" void kernel_launch(void* const* d_in, const int* in_sizes, int n_in,
                              void* d_out, int out_size, void* d_ws, size_t ws_size,
                              hipStream_t stream) {
    const float* x   = (const float*)d_in[0];
    const void*  ei  = d_in[1];
    const float* ew  = (const float*)d_in[2];
    const float* W1  = (const float*)d_in[3];
    const float* b1  = (const float*)d_in[4];
    const float* W2  = (const float*)d_in[5];
    const float* b2  = (const float*)d_in[6];

    const int n = in_sizes[0] / F_IN;        // 50000
    const int E = in_sizes[2];               // 1600000

    // output segments (return order)
    float* lsm  = (float*)d_out;                                   // [n*CLS]
    float* xout = lsm + (size_t)n * CLS;                           // [n*CLS]
    float* cosO = xout + (size_t)n * CLS;                          // [E]
    float* gnnO = cosO + E;                                        // [E]
    float* smO  = gnnO + E;                                        // [n*CLS]

    // workspace layout (256B aligned)
    char* w = (char*)d_ws;
    auto alloc = [&](size_t bytes) {
        char* p = w;
        w += (bytes + 255) & ~(size_t)255;
        return p;
    };
    const int NBLK  = (E + EPB - 1) / EPB;   // 196 hist/scatter blocks
    const int NBUCK = (n + 255) / 256;       // 196 buckets (dst>>8)

    uint_t*   pair   = (uint_t*)  alloc((size_t)E * 4);
    uint_t*   bkt    = (uint_t*)  alloc((size_t)E * 4);
    ushort_t* csr16  = (ushort_t*)alloc((size_t)E * 2);
    int*      ghist  = (int*)     alloc((size_t)NBLK * 256 * 4);
    int*      btot   = (int*)     alloc(256 * 4);
    int*      bbase  = (int*)     alloc(257 * 4);
    int*      rowptr = (int*)     alloc(((size_t)n + 1) * 4);
    float*    dinv   = (float*)   alloc((size_t)n * 4);
    ushort_t* xws    = (ushort_t*)alloc((size_t)n * HID * 2);
    ushort_t* hws    = (ushort_t*)alloc((size_t)n * HID * 2);   // padded to 64 ch
    ushort_t* xoutb  = (ushort_t*)alloc((size_t)n * CLS * 2);
    float*    rnorm  = (float*)   alloc((size_t)n * 4);
    ushort_t* W1s    = (ushort_t*)alloc((size_t)4 * 8 * 64 * 8 * 2);   // 32 KB
    int*      flag   = (int*)     alloc(64);

    detect_kernel<<<1, 64, 0, stream>>>((const int*)ei, flag);
    convert_w1_kernel<<<8, 256, 0, stream>>>(W1, W1s);
    build_hist_kernel<<<NBLK, 256, 0, stream>>>(ei, flag, pair, ghist, E);
    scan_cols_kernel<<<256, 64, 0, stream>>>(ghist, btot, NBLK);
    scan_base_kernel<<<1, 256, 0, stream>>>(btot, bbase);
    scatter_buckets_kernel<<<NBLK, 256, 0, stream>>>(pair, ghist, bbase, bkt, E);
    bucket_csr_kernel<<<NBUCK, 256, 0, stream>>>(bkt, bbase, csr16, rowptr, dinv, n, E, NBUCK);
    gemm1_mfma_kernel<<<(n + 15) / 16, 256, 0, stream>>>(x, W1s, dinv, xws, n);
    gather1_gemm2_kernel<<<((size_t)n * 64 + 255) / 256, 256, 0, stream>>>(rowptr, csr16, xws, dinv,
                                                                           b1, W2, hws, n);
    gather2_fin_kernel<<<((size_t)n * 64 + 255) / 256, 256, 0, stream>>>(rowptr, csr16, hws, dinv, b2,
                                                                         xout, lsm, smO, xoutb, rnorm, n);
    edge_kernel<<<(E + 255) / 256, 256, 0, stream>>>(pair, ew, xoutb, rnorm, cosO, gnnO, E);
}

// Round 8
// 295.100 us; speedup vs baseline: 1.4262x; 1.0460x over previous
//
#include <hip/hip_runtime.h>
#include <hip/hip_bf16.h>

#define F_IN 256
#define HID  64
#define CLS  40
#define EPS  1e-8f
#define XS_STRIDE 264   // halfwords per LDS x-tile row: 2-way max bank aliasing (free)
#define EPB  8192       // edges per block in hist/scatter passes (256 thr x 32)

typedef unsigned short ushort_t;
typedef unsigned int   uint_t;
typedef __attribute__((ext_vector_type(8))) short bf16x8;
typedef __attribute__((ext_vector_type(4))) float f32x4;

__device__ __forceinline__ float bf2f(ushort_t u) {
    union { uint_t i; float f; } v; v.i = ((uint_t)u) << 16; return v.f;
}
__device__ __forceinline__ ushort_t f2bf(float f) {
    union { float f; uint_t i; } v; v.f = f;
    uint_t r = v.i + 0x7fff + ((v.i >> 16) & 1);          // RNE
    return (ushort_t)(r >> 16);
}
__device__ __forceinline__ float blo(uint_t p) {
    union { uint_t i; float f; } v; v.i = p << 16; return v.f;
}
__device__ __forceinline__ float bhi(uint_t p) {
    union { uint_t i; float f; } v; v.i = p & 0xffff0000u; return v.f;
}
__device__ __forceinline__ float dot_u4(uint4 a, uint4 b) {
    return blo(a.x) * blo(b.x) + bhi(a.x) * bhi(b.x)
         + blo(a.y) * blo(b.y) + bhi(a.y) * bhi(b.y)
         + blo(a.z) * blo(b.z) + bhi(a.z) * bhi(b.z)
         + blo(a.w) * blo(b.w) + bhi(a.w) * bhi(b.w);
}

// -------------------- dtype detection (int64 vs int32 edge_index) -----------
__global__ void detect_kernel(const int* __restrict__ raw, int* __restrict__ flag) {
    int c = threadIdx.x;                  // one wave
    int w = raw[2 * c + 1];               // odd int32 words
    unsigned long long b = __ballot(w != 0);
    if (c == 0) *flag = (b == 0ULL) ? 1 : 0;   // all zero -> int64 layout
}

// ---- pass 1: pair packing + per-block bucket histogram (dst>>8) ------------
__global__ void build_hist_kernel(const void* __restrict__ raw, const int* __restrict__ flag,
                                  uint_t* __restrict__ pair, int* __restrict__ ghist, int E) {
    __shared__ int lhist[256];
    int tid = threadIdx.x;
    lhist[tid] = 0;
    __syncthreads();
    int base = blockIdx.x * EPB;
    if (*flag) {
        const long long* r = (const long long*)raw;
        for (int it = 0; it < EPB / 1024; ++it) {        // 4 edges/thread/iter
            int e = base + (it * 256 + tid) * 4;
            if (e + 4 <= E) {
                ulonglong2 a0 = *(const ulonglong2*)(r + e);
                ulonglong2 a1 = *(const ulonglong2*)(r + e + 2);
                ulonglong2 b0 = *(const ulonglong2*)(r + E + e);
                ulonglong2 b1 = *(const ulonglong2*)(r + E + e + 2);
                uint_t d0 = (uint_t)b0.x, d1 = (uint_t)b0.y;
                uint_t d2 = (uint_t)b1.x, d3 = (uint_t)b1.y;
                uint4 p;
                p.x = (d0 << 16) | (uint_t)a0.x;
                p.y = (d1 << 16) | (uint_t)a0.y;
                p.z = (d2 << 16) | (uint_t)a1.x;
                p.w = (d3 << 16) | (uint_t)a1.y;
                *(uint4*)(pair + e) = p;
                atomicAdd(&lhist[d0 >> 8], 1);
                atomicAdd(&lhist[d1 >> 8], 1);
                atomicAdd(&lhist[d2 >> 8], 1);
                atomicAdd(&lhist[d3 >> 8], 1);
            } else {
                for (int k = 0; k < 4; ++k) {
                    int ee = e + k;
                    if (ee < E) {
                        uint_t s = (uint_t)r[ee];
                        uint_t d = (uint_t)r[E + ee];
                        pair[ee] = (d << 16) | s;
                        atomicAdd(&lhist[d >> 8], 1);
                    }
                }
            }
        }
    } else {
        const int* r = (const int*)raw;
        for (int it = 0; it < EPB / 1024; ++it) {        // 4 edges/thread/iter
            int e = base + (it * 256 + tid) * 4;
            if (e + 4 <= E) {
                int4 a = *(const int4*)(r + e);
                int4 b = *(const int4*)(r + E + e);
                uint_t d0 = (uint_t)b.x, d1 = (uint_t)b.y;
                uint_t d2 = (uint_t)b.z, d3 = (uint_t)b.w;
                uint4 p;
                p.x = (d0 << 16) | (uint_t)a.x;
                p.y = (d1 << 16) | (uint_t)a.y;
                p.z = (d2 << 16) | (uint_t)a.z;
                p.w = (d3 << 16) | (uint_t)a.w;
                *(uint4*)(pair + e) = p;
                atomicAdd(&lhist[d0 >> 8], 1);
                atomicAdd(&lhist[d1 >> 8], 1);
                atomicAdd(&lhist[d2 >> 8], 1);
                atomicAdd(&lhist[d3 >> 8], 1);
            } else {
                for (int k = 0; k < 4; ++k) {
                    int ee = e + k;
                    if (ee < E) {
                        uint_t s = (uint_t)r[ee];
                        uint_t d = (uint_t)r[E + ee];
                        pair[ee] = (d << 16) | s;
                        atomicAdd(&lhist[d >> 8], 1);
                    }
                }
            }
        }
    }
    __syncthreads();
    ghist[blockIdx.x * 256 + tid] = lhist[tid];
}

// ---- pass 2a: PARALLEL column scan — one wave per bucket -------------------
__global__ void scan_cols_kernel(int* __restrict__ ghist, int* __restrict__ btot,
                                 int NBLK) {
    int k    = blockIdx.x;                 // bucket 0..255
    int lane = threadIdx.x;                // 0..63
    int carry = 0;
    for (int b0 = 0; b0 < NBLK; b0 += 64) {
        int b = b0 + lane;
        int v = (b < NBLK) ? ghist[b * 256 + k] : 0;
        int x = v;
        #pragma unroll
        for (int o = 1; o < 64; o <<= 1) {
            int t = __shfl_up(x, o);
            if (lane >= o) x += t;
        }
        if (b < NBLK) ghist[b * 256 + k] = carry + x - v;   // exclusive offset
        carry += __shfl(x, 63);            // batch total
    }
    if (lane == 0) btot[k] = carry;        // bucket total
}

// ---- pass 2b (1 block): exclusive scan of bucket totals -> bucket bases ----
__global__ void scan_base_kernel(const int* __restrict__ btot, int* __restrict__ bbase) {
    __shared__ int s[256];
    int k = threadIdx.x;
    int v = btot[k];
    int x = v;
    s[k] = x;
    __syncthreads();
    #pragma unroll
    for (int o = 1; o < 256; o <<= 1) {
        int t = (k >= o) ? s[k - o] : 0;
        __syncthreads();
        x += t;
        s[k] = x;
        __syncthreads();
    }
    bbase[k] = x - v;                      // exclusive bucket base
    if (k == 255) bbase[256] = x;          // == E
}

// ---- pass 3: scatter edges into bucket regions (LDS cursors only) ----------
__global__ void scatter_buckets_kernel(const uint_t* __restrict__ pair,
                                       const int* __restrict__ ghist,
                                       const int* __restrict__ bbase,
                                       uint_t* __restrict__ bkt, int E) {
    __shared__ int cursor[256];
    int tid = threadIdx.x;
    cursor[tid] = ghist[blockIdx.x * 256 + tid] + bbase[tid];
    __syncthreads();
    int base = blockIdx.x * EPB;
    for (int it = 0; it < EPB / 256; ++it) {
        int e = base + it * 256 + tid;
        if (e < E) {
            uint_t u = pair[e];
            int pos = atomicAdd(&cursor[u >> 24], 1);   // LDS atomic, returns rank
            bkt[pos] = u;
        }
    }
}

// ---- pass 4: one block per bucket -> deg/rowptr/dinv + sorted csr16 --------
__global__ void bucket_csr_kernel(const uint_t* __restrict__ bkt,
                                  const int* __restrict__ bbase,
                                  ushort_t* __restrict__ csr, int* __restrict__ rowptr,
                                  float* __restrict__ dinv, int n, int E, int NBUCK) {
    __shared__ int lhist[256];
    __shared__ int lscan[256];
    __shared__ int cursor[256];
    int tid = threadIdx.x;
    int kb  = blockIdx.x;
    int base = bbase[kb];
    int cnt  = bbase[kb + 1] - base;
    lhist[tid] = 0;
    __syncthreads();
    for (int i = tid; i < cnt; i += 256) {            // pass A: exact degrees
        uint_t u = bkt[base + i];
        atomicAdd(&lhist[(u >> 16) & 255], 1);
    }
    __syncthreads();
    int v = lhist[tid];                        // degree of node kb*256+tid (no self-loop)
    int x = v;
    lscan[tid] = x;
    __syncthreads();
    #pragma unroll
    for (int o = 1; o < 256; o <<= 1) {
        int t = (tid >= o) ? lscan[tid - o] : 0;
        __syncthreads();
        x += t;
        lscan[tid] = x;
        __syncthreads();
    }
    int excl = x - v;                          // exclusive scan within bucket
    int node = kb * 256 + tid;
    if (node < n) {
        rowptr[node] = base + excl;
        dinv[node]   = rsqrtf((float)(v + 1)); // +1 self-loop
    }
    cursor[tid] = base + excl;
    if (kb == NBUCK - 1 && tid == 0) rowptr[n] = E;
    __syncthreads();
    for (int i = tid; i < cnt; i += 256) {            // pass B: place src
        uint_t u = bkt[base + i];                     // L2 hit (just touched)
        int pos = atomicAdd(&cursor[(u >> 16) & 255], 1);   // LDS atomic
        csr[pos] = (ushort_t)(u & 0xffffu);    // 2B scatter, block-local region
    }
}

// ---- W1 -> bf16, pre-swizzled into MFMA B-fragment order -------------------
__global__ void convert_w1_kernel(const float* __restrict__ W1, ushort_t* __restrict__ W1s) {
    int t = blockIdx.x * blockDim.x + threadIdx.x;   // 2048 triples
    if (t >= 4 * 8 * 64) return;
    int lane = t & 63;
    int kk   = (t >> 6) & 7;
    int nt   = t >> 9;
    int col  = nt * 16 + (lane & 15);
    int k0   = kk * 32 + (lane >> 4) * 8;
    ushort_t v[8];
    #pragma unroll
    for (int j = 0; j < 8; ++j) v[j] = f2bf(W1[(size_t)(k0 + j) * HID + col]);
    uint4 p;
    p.x = (uint_t)v[0] | ((uint_t)v[1] << 16);
    p.y = (uint_t)v[2] | ((uint_t)v[3] << 16);
    p.z = (uint_t)v[4] | ((uint_t)v[5] << 16);
    p.w = (uint_t)v[6] | ((uint_t)v[7] << 16);
    *(uint4*)(W1s + (size_t)t * 8) = p;
}

// ------- layer 1 GEMM on MFMA: xws = bf16((x @ W1) * dinv[node]) ------------
__global__ void gemm1_mfma_kernel(const float* __restrict__ x,
                                  const ushort_t* __restrict__ W1s,
                                  const float* __restrict__ dinv,
                                  ushort_t* __restrict__ xws, int n) {
    __shared__ ushort_t xs[16 * XS_STRIDE];           // 8448 B bf16 x-tile
    int node0 = blockIdx.x * 16;
    int tid = threadIdx.x;
    for (int i = tid; i < 16 * 64; i += 256) {        // stage x tile -> bf16 LDS
        int r  = i >> 6;
        int c4 = (i & 63) << 2;
        int node = node0 + r;
        float4 v = (node < n) ? *(const float4*)(x + (size_t)node * F_IN + c4)
                              : make_float4(0.f, 0.f, 0.f, 0.f);
        ushort4 b;
        b.x = f2bf(v.x); b.y = f2bf(v.y); b.z = f2bf(v.z); b.w = f2bf(v.w);
        *(ushort4*)(&xs[r * XS_STRIDE + c4]) = b;     // 8B-aligned ds_write_b64
    }
    __syncthreads();
    int wave = tid >> 6;                              // N-tile index 0..3
    int lane = tid & 63;
    int m    = lane & 15;
    int q    = lane >> 4;
    f32x4 acc = {0.f, 0.f, 0.f, 0.f};
    #pragma unroll
    for (int kk = 0; kk < 8; ++kk) {                  // K = 8 x 32
        bf16x8 a = *(const bf16x8*)(&xs[m * XS_STRIDE + kk * 32 + q * 8]);
        bf16x8 b = *(const bf16x8*)(W1s + (((size_t)wave * 8 + kk) * 64 + lane) * 8);
        acc = __builtin_amdgcn_mfma_f32_16x16x32_bf16(a, b, acc, 0, 0, 0);
    }
    int ch = wave * 16 + m;                           // C/D: col=lane&15, row=q*4+r
    #pragma unroll
    for (int r = 0; r < 4; ++r) {
        int node = node0 + q * 4 + r;
        if (node < n)
            xws[(size_t)node * HID + ch] = f2bf(acc[r] * dinv[node]);
    }
}

// ---- fused: gather1 (h = relu(dinv*(sum)+b1)) + gemm2 (hws = h@W2 * dinv) --
// one wave per node; 8 lane-groups x 16B = one dwordx4 instruction fetches
// 8 edge-rows (1KB). Indices via csr[ch + (l>>3)] (one 16B line, no shfl).
// acc8[8] per lane; cross-group xor-reduce (^8,^16,^32) at the end.
__global__ void gather1_gemm2_kernel(const int* __restrict__ rowptr,
                                     const ushort_t* __restrict__ csr,
                                     const ushort_t* __restrict__ xws,
                                     const float* __restrict__ dinv,
                                     const float* __restrict__ b1,
                                     const float* __restrict__ W2,
                                     ushort_t* __restrict__ hws, int n) {
    __shared__ float hbuf[4][72];
    __shared__ float w2s[HID * CLS];                  // 10240 B
    int tid  = threadIdx.x;
    int wave = tid >> 6;
    int l    = tid & 63;
    int g    = l >> 3;                                // row-group 0..7
    int lc   = l & 7;                                 // channel-group (8 ch each)
    for (int i = tid; i < HID * CLS / 4; i += 256)
        *(float4*)(&w2s[i * 4]) = *(const float4*)(W2 + i * 4);
    int wv = (blockIdx.x * blockDim.x + tid) >> 6;
    bool active = wv < n;
    int beg = 0, endp = 0;
    float di = 0.f;
    float acc8[8];
    #pragma unroll
    for (int j = 0; j < 8; ++j) acc8[j] = 0.f;
    if (active) {
        beg = rowptr[wv]; endp = rowptr[wv + 1];
        di  = dinv[wv];
        if (l < 8) {                                  // self-loop: group 0 only
            uint4 sv = *(const uint4*)(xws + (size_t)wv * HID + lc * 8);
            acc8[0] = blo(sv.x); acc8[1] = bhi(sv.x);
            acc8[2] = blo(sv.y); acc8[3] = bhi(sv.y);
            acc8[4] = blo(sv.z); acc8[5] = bhi(sv.z);
            acc8[6] = blo(sv.w); acc8[7] = bhi(sv.w);
        }
    }
    for (int ch = beg; ch < endp; ch += 32) {         // 32 edges per iteration
        #pragma unroll
        for (int k = 0; k < 4; ++k) {                 // 4 independent 8-row loads
            int e = ch + k * 8 + g;
            bool val = e < endp;
            int ec = val ? e : (endp - 1);            // clamp, mask value below
            int s = (int)csr[ec];                     // 64 lanes -> one 16B line
            uint4 p = *(const uint4*)(xws + (size_t)s * HID + lc * 8);
            if (!val) { p.x = 0u; p.y = 0u; p.z = 0u; p.w = 0u; }
            acc8[0] += blo(p.x); acc8[1] += bhi(p.x);
            acc8[2] += blo(p.y); acc8[3] += bhi(p.y);
            acc8[4] += blo(p.z); acc8[5] += bhi(p.z);
            acc8[6] += blo(p.w); acc8[7] += bhi(p.w);
        }
    }
    #pragma unroll
    for (int j = 0; j < 8; ++j) {                     // sum the 8 row-groups
        float v = acc8[j];
        v += __shfl_xor(v, 8);
        v += __shfl_xor(v, 16);
        v += __shfl_xor(v, 32);
        acc8[j] = v;
    }
    if (active && l < 8) {                            // group 0 writes h row
        #pragma unroll
        for (int j = 0; j < 8; ++j)
            hbuf[wave][lc * 8 + j] = fmaxf(acc8[j] * di + b1[lc * 8 + j], 0.f);
    }
    __syncthreads();                                  // covers w2s + hbuf
    if (active) {
        if (l < CLS) {
            float o = 0.f;
            const float* hr = hbuf[wave];
            #pragma unroll 16
            for (int k = 0; k < HID; ++k) o += hr[k] * w2s[k * CLS + l];
            hws[(size_t)wv * HID + l] = f2bf(o * di);
        } else {
            hws[(size_t)wv * HID + l] = 0;            // zero-pad ch 40..63
        }
    }
}

// ---------- layer 2 gather fused with finalize ------------------------------
// hws rows padded to 64 bf16 (128B) -> identical 8x8 load structure.
// Stores PRE-NORMALIZED bf16 rows (raw * rnorm): edge dot == cosine directly.
__global__ void gather2_fin_kernel(const int* __restrict__ rowptr,
                                   const ushort_t* __restrict__ csr,
                                   const ushort_t* __restrict__ hws,
                                   const float* __restrict__ dinv,
                                   const float* __restrict__ b2,
                                   float* __restrict__ xout, float* __restrict__ lsm,
                                   float* __restrict__ sm, ushort_t* __restrict__ xnb,
                                   int n) {
    int tid = threadIdx.x;
    int wv  = (blockIdx.x * blockDim.x + tid) >> 6;
    if (wv >= n) return;
    int l  = tid & 63;
    int g  = l >> 3;
    int lc = l & 7;                                   // channels lc*8..lc*8+7
    int beg = rowptr[wv], endp = rowptr[wv + 1];
    float di = dinv[wv];
    float acc8[8];
    #pragma unroll
    for (int j = 0; j < 8; ++j) acc8[j] = 0.f;
    if (l < 8) {                                      // self-loop term
        uint4 sv = *(const uint4*)(hws + (size_t)wv * HID + lc * 8);
        acc8[0] = blo(sv.x); acc8[1] = bhi(sv.x);
        acc8[2] = blo(sv.y); acc8[3] = bhi(sv.y);
        acc8[4] = blo(sv.z); acc8[5] = bhi(sv.z);
        acc8[6] = blo(sv.w); acc8[7] = bhi(sv.w);
    }
    for (int ch = beg; ch < endp; ch += 32) {
        #pragma unroll
        for (int k = 0; k < 4; ++k) {
            int e = ch + k * 8 + g;
            bool val = e < endp;
            int ec = val ? e : (endp - 1);
            int s = (int)csr[ec];
            uint4 p = *(const uint4*)(hws + (size_t)s * HID + lc * 8);
            if (!val) { p.x = 0u; p.y = 0u; p.z = 0u; p.w = 0u; }
            acc8[0] += blo(p.x); acc8[1] += bhi(p.x);
            acc8[2] += blo(p.y); acc8[3] += bhi(p.y);
            acc8[4] += blo(p.z); acc8[5] += bhi(p.z);
            acc8[6] += blo(p.w); acc8[7] += bhi(p.w);
        }
    }
    #pragma unroll
    for (int j = 0; j < 8; ++j) {
        float v = acc8[j];
        v += __shfl_xor(v, 8);
        v += __shfl_xor(v, 16);
        v += __shfl_xor(v, 32);
        acc8[j] = v;
    }
    bool cgv = lc < 5;                                // 40 = 5 groups x 8 ch
    float raw[8];
    if (cgv) {
        #pragma unroll
        for (int j = 0; j < 8; ++j) raw[j] = acc8[j] * di + b2[lc * 8 + j];
    } else {
        #pragma unroll
        for (int j = 0; j < 8; ++j) raw[j] = 0.f;
    }
    float mx = -3.0e38f;
    if (cgv) {
        #pragma unroll
        for (int j = 0; j < 8; ++j) mx = fmaxf(mx, raw[j]);
    }
    mx = fmaxf(mx, __shfl_xor(mx, 1));
    mx = fmaxf(mx, __shfl_xor(mx, 2));
    mx = fmaxf(mx, __shfl_xor(mx, 4));
    float ex[8];
    float ls = 0.f;
    if (cgv) {
        #pragma unroll
        for (int j = 0; j < 8; ++j) { ex[j] = __expf(raw[j] - mx); ls += ex[j]; }
    } else {
        #pragma unroll
        for (int j = 0; j < 8; ++j) ex[j] = 0.f;
    }
    ls += __shfl_xor(ls, 1);
    ls += __shfl_xor(ls, 2);
    ls += __shfl_xor(ls, 4);
    float sq = 0.f;
    if (cgv) {
        #pragma unroll
        for (int j = 0; j < 8; ++j) sq += raw[j] * raw[j];
    }
    sq += __shfl_xor(sq, 1);
    sq += __shfl_xor(sq, 2);
    sq += __shfl_xor(sq, 4);
    float rn = 1.0f / fmaxf(sqrtf(sq), EPS);          // all lanes have full sq
    if (l < 5) {                                      // lanes 0..4 write row
        size_t fb = (size_t)wv * CLS + l * 8;
        *(float4*)(xout + fb)     = make_float4(raw[0], raw[1], raw[2], raw[3]);
        *(float4*)(xout + fb + 4) = make_float4(raw[4], raw[5], raw[6], raw[7]);
        float lse = mx + __logf(ls);
        *(float4*)(lsm + fb)     = make_float4(raw[0] - lse, raw[1] - lse, raw[2] - lse, raw[3] - lse);
        *(float4*)(lsm + fb + 4) = make_float4(raw[4] - lse, raw[5] - lse, raw[6] - lse, raw[7] - lse);
        float inv = 1.0f / ls;
        *(float4*)(sm + fb)     = make_float4(ex[0] * inv, ex[1] * inv, ex[2] * inv, ex[3] * inv);
        *(float4*)(sm + fb + 4) = make_float4(ex[4] * inv, ex[5] * inv, ex[6] * inv, ex[7] * inv);
        uint4 pb;                                     // normalized bf16 row
        pb.x = (uint_t)f2bf(raw[0] * rn) | ((uint_t)f2bf(raw[1] * rn) << 16);
        pb.y = (uint_t)f2bf(raw[2] * rn) | ((uint_t)f2bf(raw[3] * rn) << 16);
        pb.z = (uint_t)f2bf(raw[4] * rn) | ((uint_t)f2bf(raw[5] * rn) << 16);
        pb.w = (uint_t)f2bf(raw[6] * rn) | ((uint_t)f2bf(raw[7] * rn) << 16);
        *(uint4*)(xnb + fb) = pb;                     // byte off = wv*80+l*16
    }
}

// ------------- per-edge cosine dissimilarity + gnn_edge ---------------------
// 8 lanes per edge: lane j<5 loads 16B chunk j of BOTH normalized rows ->
// intra-wave coalesced (each row = ~2 line transactions, not 5x64 lanes).
// dot partials reduced via shfl_xor ^1,^2,^4; rows pre-normalized -> dot = cos.
__global__ void edge_kernel(const uint_t* __restrict__ pair,
                            const float* __restrict__ ew, const ushort_t* __restrict__ xnb,
                            float* __restrict__ cos_out, float* __restrict__ gnn_out, int E) {
    int tid = threadIdx.x;
    int wid = (blockIdx.x * blockDim.x + tid) >> 6;   // global wave id
    int l = tid & 63;
    int g = l >> 3;                                   // edge slot 0..7
    int j = l & 7;                                    // 16B chunk slot
    int e = wid * 8 + g;
    if (e >= E) return;
    uint_t u = pair[e];                               // 8 lanes same addr -> bcast
    int s = (int)(u & 0xffffu);
    int d = (int)(u >> 16);
    float part = 0.f;
    if (j < 5) {                                      // rows are 80B = 5 x 16B
        uint4 a = *(const uint4*)(xnb + (size_t)s * CLS + j * 8);
        uint4 b = *(const uint4*)(xnb + (size_t)d * CLS + j * 8);
        part = dot_u4(a, b);
    }
    part += __shfl_xor(part, 1);
    part += __shfl_xor(part, 2);
    part += __shfl_xor(part, 4);
    if (j == 0) {                                     // 8 leaders: 32B coalesced
        cos_out[e] = 1.0f - part;
        gnn_out[e] = (ew[e] > 0.5f) ? 1.0f : -1.0f;
    }
}

// ---------------------------------------------------------------------------
extern "C" void kernel_launch(void* const* d_in, const int* in_sizes, int n_in,
                              void* d_out, int out_size, void* d_ws, size_t ws_size,
                              hipStream_t stream) {
    const float* x   = (const float*)d_in[0];
    const void*  ei  = d_in[1];
    const float* ew  = (const float*)d_in[2];
    const float* W1  = (const float*)d_in[3];
    const float* b1  = (const float*)d_in[4];
    const float* W2  = (const float*)d_in[5];
    const float* b2  = (const float*)d_in[6];

    const int n = in_sizes[0] / F_IN;        // 50000
    const int E = in_sizes[2];               // 1600000

    // output segments (return order)
    float* lsm  = (float*)d_out;                                   // [n*CLS]
    float* xout = lsm + (size_t)n * CLS;                           // [n*CLS]
    float* cosO = xout + (size_t)n * CLS;                          // [E]
    float* gnnO = cosO + E;                                        // [E]
    float* smO  = gnnO + E;                                        // [n*CLS]

    // workspace layout (256B aligned)
    char* w = (char*)d_ws;
    auto alloc = [&](size_t bytes) {
        char* p = w;
        w += (bytes + 255) & ~(size_t)255;
        return p;
    };
    const int NBLK  = (E + EPB - 1) / EPB;   // 196 hist/scatter blocks
    const int NBUCK = (n + 255) / 256;       // 196 buckets (dst>>8)

    uint_t*   pair   = (uint_t*)  alloc((size_t)E * 4);
    uint_t*   bkt    = (uint_t*)  alloc((size_t)E * 4);
    ushort_t* csr16  = (ushort_t*)alloc((size_t)E * 2);
    int*      ghist  = (int*)     alloc((size_t)NBLK * 256 * 4);
    int*      btot   = (int*)     alloc(256 * 4);
    int*      bbase  = (int*)     alloc(257 * 4);
    int*      rowptr = (int*)     alloc(((size_t)n + 1) * 4);
    float*    dinv   = (float*)   alloc((size_t)n * 4);
    ushort_t* xws    = (ushort_t*)alloc((size_t)n * HID * 2);
    ushort_t* hws    = (ushort_t*)alloc((size_t)n * HID * 2);   // padded to 64 ch
    ushort_t* xnb    = (ushort_t*)alloc((size_t)n * CLS * 2);   // normalized rows
    ushort_t* W1s    = (ushort_t*)alloc((size_t)4 * 8 * 64 * 8 * 2);   // 32 KB
    int*      flag   = (int*)     alloc(64);

    detect_kernel<<<1, 64, 0, stream>>>((const int*)ei, flag);
    convert_w1_kernel<<<8, 256, 0, stream>>>(W1, W1s);
    build_hist_kernel<<<NBLK, 256, 0, stream>>>(ei, flag, pair, ghist, E);
    scan_cols_kernel<<<256, 64, 0, stream>>>(ghist, btot, NBLK);
    scan_base_kernel<<<1, 256, 0, stream>>>(btot, bbase);
    scatter_buckets_kernel<<<NBLK, 256, 0, stream>>>(pair, ghist, bbase, bkt, E);
    bucket_csr_kernel<<<NBUCK, 256, 0, stream>>>(bkt, bbase, csr16, rowptr, dinv, n, E, NBUCK);
    gemm1_mfma_kernel<<<(n + 15) / 16, 256, 0, stream>>>(x, W1s, dinv, xws, n);
    gather1_gemm2_kernel<<<((size_t)n * 64 + 255) / 256, 256, 0, stream>>>(rowptr, csr16, xws, dinv,
                                                                           b1, W2, hws, n);
    gather2_fin_kernel<<<((size_t)n * 64 + 255) / 256, 256, 0, stream>>>(rowptr, csr16, hws, dinv, b2,
                                                                         xout, lsm, smO, xnb, n);
    edge_kernel<<<((size_t)E * 8 + 255) / 256, 256, 0, stream>>>(pair, ew, xnb, cosO, gnnO, E);
}

// Round 9
// 286.070 us; speedup vs baseline: 1.4713x; 1.0316x over previous
//
#include <hip/hip_runtime.h>
#include <hip/hip_bf16.h>

#define F_IN 256
#define HID  64
#define CLS  40
#define EPS  1e-8f
#define XS_STRIDE 264   // halfwords per LDS x-tile row: 2-way max bank aliasing (free)
#define EPB  8192       // edges per block in hist/scatter passes (256 thr x 32)

typedef unsigned short ushort_t;
typedef unsigned int   uint_t;
typedef __attribute__((ext_vector_type(8))) short bf16x8;
typedef __attribute__((ext_vector_type(4))) float f32x4;

__device__ __forceinline__ float bf2f(ushort_t u) {
    union { uint_t i; float f; } v; v.i = ((uint_t)u) << 16; return v.f;
}
__device__ __forceinline__ ushort_t f2bf(float f) {
    union { float f; uint_t i; } v; v.f = f;
    uint_t r = v.i + 0x7fff + ((v.i >> 16) & 1);          // RNE
    return (ushort_t)(r >> 16);
}
__device__ __forceinline__ float blo(uint_t p) {
    union { uint_t i; float f; } v; v.i = p << 16; return v.f;
}
__device__ __forceinline__ float bhi(uint_t p) {
    union { uint_t i; float f; } v; v.i = p & 0xffff0000u; return v.f;
}
__device__ __forceinline__ float dot_u4(uint4 a, uint4 b) {
    return blo(a.x) * blo(b.x) + bhi(a.x) * bhi(b.x)
         + blo(a.y) * blo(b.y) + bhi(a.y) * bhi(b.y)
         + blo(a.z) * blo(b.z) + bhi(a.z) * bhi(b.z)
         + blo(a.w) * blo(b.w) + bhi(a.w) * bhi(b.w);
}

// -------------------- dtype detection (int64 vs int32 edge_index) -----------
__global__ void detect_kernel(const int* __restrict__ raw, int* __restrict__ flag) {
    int c = threadIdx.x;                  // one wave
    int w = raw[2 * c + 1];               // odd int32 words
    unsigned long long b = __ballot(w != 0);
    if (c == 0) *flag = (b == 0ULL) ? 1 : 0;   // all zero -> int64 layout
}

// ---- pass 1: pair packing + per-block bucket histogram (dst>>8) ------------
__global__ void build_hist_kernel(const void* __restrict__ raw, const int* __restrict__ flag,
                                  uint_t* __restrict__ pair, int* __restrict__ ghist, int E) {
    __shared__ int lhist[256];
    int tid = threadIdx.x;
    lhist[tid] = 0;
    __syncthreads();
    int base = blockIdx.x * EPB;
    if (*flag) {
        const long long* r = (const long long*)raw;
        for (int it = 0; it < EPB / 1024; ++it) {        // 4 edges/thread/iter
            int e = base + (it * 256 + tid) * 4;
            if (e + 4 <= E) {
                ulonglong2 a0 = *(const ulonglong2*)(r + e);
                ulonglong2 a1 = *(const ulonglong2*)(r + e + 2);
                ulonglong2 b0 = *(const ulonglong2*)(r + E + e);
                ulonglong2 b1 = *(const ulonglong2*)(r + E + e + 2);
                uint_t d0 = (uint_t)b0.x, d1 = (uint_t)b0.y;
                uint_t d2 = (uint_t)b1.x, d3 = (uint_t)b1.y;
                uint4 p;
                p.x = (d0 << 16) | (uint_t)a0.x;
                p.y = (d1 << 16) | (uint_t)a0.y;
                p.z = (d2 << 16) | (uint_t)a1.x;
                p.w = (d3 << 16) | (uint_t)a1.y;
                *(uint4*)(pair + e) = p;
                atomicAdd(&lhist[d0 >> 8], 1);
                atomicAdd(&lhist[d1 >> 8], 1);
                atomicAdd(&lhist[d2 >> 8], 1);
                atomicAdd(&lhist[d3 >> 8], 1);
            } else {
                for (int k = 0; k < 4; ++k) {
                    int ee = e + k;
                    if (ee < E) {
                        uint_t s = (uint_t)r[ee];
                        uint_t d = (uint_t)r[E + ee];
                        pair[ee] = (d << 16) | s;
                        atomicAdd(&lhist[d >> 8], 1);
                    }
                }
            }
        }
    } else {
        const int* r = (const int*)raw;
        for (int it = 0; it < EPB / 1024; ++it) {        // 4 edges/thread/iter
            int e = base + (it * 256 + tid) * 4;
            if (e + 4 <= E) {
                int4 a = *(const int4*)(r + e);
                int4 b = *(const int4*)(r + E + e);
                uint_t d0 = (uint_t)b.x, d1 = (uint_t)b.y;
                uint_t d2 = (uint_t)b.z, d3 = (uint_t)b.w;
                uint4 p;
                p.x = (d0 << 16) | (uint_t)a.x;
                p.y = (d1 << 16) | (uint_t)a.y;
                p.z = (d2 << 16) | (uint_t)a.z;
                p.w = (d3 << 16) | (uint_t)a.w;
                *(uint4*)(pair + e) = p;
                atomicAdd(&lhist[d0 >> 8], 1);
                atomicAdd(&lhist[d1 >> 8], 1);
                atomicAdd(&lhist[d2 >> 8], 1);
                atomicAdd(&lhist[d3 >> 8], 1);
            } else {
                for (int k = 0; k < 4; ++k) {
                    int ee = e + k;
                    if (ee < E) {
                        uint_t s = (uint_t)r[ee];
                        uint_t d = (uint_t)r[E + ee];
                        pair[ee] = (d << 16) | s;
                        atomicAdd(&lhist[d >> 8], 1);
                    }
                }
            }
        }
    }
    __syncthreads();
    ghist[blockIdx.x * 256 + tid] = lhist[tid];
}

// ---- pass 2a: PARALLEL column scan — one wave per bucket -------------------
__global__ void scan_cols_kernel(int* __restrict__ ghist, int* __restrict__ btot,
                                 int NBLK) {
    int k    = blockIdx.x;                 // bucket 0..255
    int lane = threadIdx.x;                // 0..63
    int carry = 0;
    for (int b0 = 0; b0 < NBLK; b0 += 64) {
        int b = b0 + lane;
        int v = (b < NBLK) ? ghist[b * 256 + k] : 0;
        int x = v;
        #pragma unroll
        for (int o = 1; o < 64; o <<= 1) {
            int t = __shfl_up(x, o);
            if (lane >= o) x += t;
        }
        if (b < NBLK) ghist[b * 256 + k] = carry + x - v;   // exclusive offset
        carry += __shfl(x, 63);            // batch total
    }
    if (lane == 0) btot[k] = carry;        // bucket total
}

// ---- pass 2b (1 block): exclusive scan of bucket totals -> bucket bases ----
__global__ void scan_base_kernel(const int* __restrict__ btot, int* __restrict__ bbase) {
    __shared__ int s[256];
    int k = threadIdx.x;
    int v = btot[k];
    int x = v;
    s[k] = x;
    __syncthreads();
    #pragma unroll
    for (int o = 1; o < 256; o <<= 1) {
        int t = (k >= o) ? s[k - o] : 0;
        __syncthreads();
        x += t;
        s[k] = x;
        __syncthreads();
    }
    bbase[k] = x - v;                      // exclusive bucket base
    if (k == 255) bbase[256] = x;          // == E
}

// ---- pass 3: scatter edges into bucket regions (LDS cursors only) ----------
__global__ void scatter_buckets_kernel(const uint_t* __restrict__ pair,
                                       const int* __restrict__ ghist,
                                       const int* __restrict__ bbase,
                                       uint_t* __restrict__ bkt, int E) {
    __shared__ int cursor[256];
    int tid = threadIdx.x;
    cursor[tid] = ghist[blockIdx.x * 256 + tid] + bbase[tid];
    __syncthreads();
    int base = blockIdx.x * EPB;
    for (int it = 0; it < EPB / 256; ++it) {
        int e = base + it * 256 + tid;
        if (e < E) {
            uint_t u = pair[e];
            int pos = atomicAdd(&cursor[u >> 24], 1);   // LDS atomic, returns rank
            bkt[pos] = u;
        }
    }
}

// ---- pass 4: one block per bucket -> deg/rowptr/dinv + sorted csr16 --------
__global__ void bucket_csr_kernel(const uint_t* __restrict__ bkt,
                                  const int* __restrict__ bbase,
                                  ushort_t* __restrict__ csr, int* __restrict__ rowptr,
                                  float* __restrict__ dinv, int n, int E, int NBUCK) {
    __shared__ int lhist[256];
    __shared__ int lscan[256];
    __shared__ int cursor[256];
    int tid = threadIdx.x;
    int kb  = blockIdx.x;
    int base = bbase[kb];
    int cnt  = bbase[kb + 1] - base;
    lhist[tid] = 0;
    __syncthreads();
    for (int i = tid; i < cnt; i += 256) {            // pass A: exact degrees
        uint_t u = bkt[base + i];
        atomicAdd(&lhist[(u >> 16) & 255], 1);
    }
    __syncthreads();
    int v = lhist[tid];                        // degree of node kb*256+tid (no self-loop)
    int x = v;
    lscan[tid] = x;
    __syncthreads();
    #pragma unroll
    for (int o = 1; o < 256; o <<= 1) {
        int t = (tid >= o) ? lscan[tid - o] : 0;
        __syncthreads();
        x += t;
        lscan[tid] = x;
        __syncthreads();
    }
    int excl = x - v;                          // exclusive scan within bucket
    int node = kb * 256 + tid;
    if (node < n) {
        rowptr[node] = base + excl;
        dinv[node]   = rsqrtf((float)(v + 1)); // +1 self-loop
    }
    cursor[tid] = base + excl;
    if (kb == NBUCK - 1 && tid == 0) rowptr[n] = E;
    __syncthreads();
    for (int i = tid; i < cnt; i += 256) {            // pass B: place src
        uint_t u = bkt[base + i];                     // L2 hit (just touched)
        int pos = atomicAdd(&cursor[(u >> 16) & 255], 1);   // LDS atomic
        csr[pos] = (ushort_t)(u & 0xffffu);    // 2B scatter, block-local region
    }
}

// ---- W1 -> bf16, pre-swizzled into MFMA B-fragment order -------------------
__global__ void convert_w1_kernel(const float* __restrict__ W1, ushort_t* __restrict__ W1s) {
    int t = blockIdx.x * blockDim.x + threadIdx.x;   // 2048 triples
    if (t >= 4 * 8 * 64) return;
    int lane = t & 63;
    int kk   = (t >> 6) & 7;
    int nt   = t >> 9;
    int col  = nt * 16 + (lane & 15);
    int k0   = kk * 32 + (lane >> 4) * 8;
    ushort_t v[8];
    #pragma unroll
    for (int j = 0; j < 8; ++j) v[j] = f2bf(W1[(size_t)(k0 + j) * HID + col]);
    uint4 p;
    p.x = (uint_t)v[0] | ((uint_t)v[1] << 16);
    p.y = (uint_t)v[2] | ((uint_t)v[3] << 16);
    p.z = (uint_t)v[4] | ((uint_t)v[5] << 16);
    p.w = (uint_t)v[6] | ((uint_t)v[7] << 16);
    *(uint4*)(W1s + (size_t)t * 8) = p;
}

// ------- layer 1 GEMM on MFMA: xws = bf16((x @ W1) * dinv[node]) ------------
__global__ void gemm1_mfma_kernel(const float* __restrict__ x,
                                  const ushort_t* __restrict__ W1s,
                                  const float* __restrict__ dinv,
                                  ushort_t* __restrict__ xws, int n) {
    __shared__ ushort_t xs[16 * XS_STRIDE];           // 8448 B bf16 x-tile
    int node0 = blockIdx.x * 16;
    int tid = threadIdx.x;
    for (int i = tid; i < 16 * 64; i += 256) {        // stage x tile -> bf16 LDS
        int r  = i >> 6;
        int c4 = (i & 63) << 2;
        int node = node0 + r;
        float4 v = (node < n) ? *(const float4*)(x + (size_t)node * F_IN + c4)
                              : make_float4(0.f, 0.f, 0.f, 0.f);
        ushort4 b;
        b.x = f2bf(v.x); b.y = f2bf(v.y); b.z = f2bf(v.z); b.w = f2bf(v.w);
        *(ushort4*)(&xs[r * XS_STRIDE + c4]) = b;     // 8B-aligned ds_write_b64
    }
    __syncthreads();
    int wave = tid >> 6;                              // N-tile index 0..3
    int lane = tid & 63;
    int m    = lane & 15;
    int q    = lane >> 4;
    f32x4 acc = {0.f, 0.f, 0.f, 0.f};
    #pragma unroll
    for (int kk = 0; kk < 8; ++kk) {                  // K = 8 x 32
        bf16x8 a = *(const bf16x8*)(&xs[m * XS_STRIDE + kk * 32 + q * 8]);
        bf16x8 b = *(const bf16x8*)(W1s + (((size_t)wave * 8 + kk) * 64 + lane) * 8);
        acc = __builtin_amdgcn_mfma_f32_16x16x32_bf16(a, b, acc, 0, 0, 0);
    }
    int ch = wave * 16 + m;                           // C/D: col=lane&15, row=q*4+r
    #pragma unroll
    for (int r = 0; r < 4; ++r) {
        int node = node0 + q * 4 + r;
        if (node < n)
            xws[(size_t)node * HID + ch] = f2bf(acc[r] * dinv[node]);
    }
}

// ---- fused: gather1 (h = relu(dinv*(sum)+b1)) + gemm2 (hws = h@W2 * dinv) --
// one wave per node; 8 lane-groups x 16B = one dwordx4 instruction fetches
// 8 edge-rows (1KB). Indices via csr[ch + (l>>3)] (one 16B line, no shfl).
// acc8[8] per lane; cross-group xor-reduce (^8,^16,^32) at the end.
__global__ void gather1_gemm2_kernel(const int* __restrict__ rowptr,
                                     const ushort_t* __restrict__ csr,
                                     const ushort_t* __restrict__ xws,
                                     const float* __restrict__ dinv,
                                     const float* __restrict__ b1,
                                     const float* __restrict__ W2,
                                     ushort_t* __restrict__ hws, int n) {
    __shared__ float hbuf[4][72];
    __shared__ float w2s[HID * CLS];                  // 10240 B
    int tid  = threadIdx.x;
    int wave = tid >> 6;
    int l    = tid & 63;
    int g    = l >> 3;                                // row-group 0..7
    int lc   = l & 7;                                 // channel-group (8 ch each)
    for (int i = tid; i < HID * CLS / 4; i += 256)
        *(float4*)(&w2s[i * 4]) = *(const float4*)(W2 + i * 4);
    int wv = (blockIdx.x * blockDim.x + tid) >> 6;
    bool active = wv < n;
    int beg = 0, endp = 0;
    float di = 0.f;
    float acc8[8];
    #pragma unroll
    for (int j = 0; j < 8; ++j) acc8[j] = 0.f;
    if (active) {
        beg = rowptr[wv]; endp = rowptr[wv + 1];
        di  = dinv[wv];
        if (l < 8) {                                  // self-loop: group 0 only
            uint4 sv = *(const uint4*)(xws + (size_t)wv * HID + lc * 8);
            acc8[0] = blo(sv.x); acc8[1] = bhi(sv.x);
            acc8[2] = blo(sv.y); acc8[3] = bhi(sv.y);
            acc8[4] = blo(sv.z); acc8[5] = bhi(sv.z);
            acc8[6] = blo(sv.w); acc8[7] = bhi(sv.w);
        }
    }
    for (int ch = beg; ch < endp; ch += 32) {         // 32 edges per iteration
        #pragma unroll
        for (int k = 0; k < 4; ++k) {                 // 4 independent 8-row loads
            int e = ch + k * 8 + g;
            bool val = e < endp;
            int ec = val ? e : (endp - 1);            // clamp, mask value below
            int s = (int)csr[ec];                     // 64 lanes -> one 16B line
            uint4 p = *(const uint4*)(xws + (size_t)s * HID + lc * 8);
            if (!val) { p.x = 0u; p.y = 0u; p.z = 0u; p.w = 0u; }
            acc8[0] += blo(p.x); acc8[1] += bhi(p.x);
            acc8[2] += blo(p.y); acc8[3] += bhi(p.y);
            acc8[4] += blo(p.z); acc8[5] += bhi(p.z);
            acc8[6] += blo(p.w); acc8[7] += bhi(p.w);
        }
    }
    #pragma unroll
    for (int j = 0; j < 8; ++j) {                     // sum the 8 row-groups
        float v = acc8[j];
        v += __shfl_xor(v, 8);
        v += __shfl_xor(v, 16);
        v += __shfl_xor(v, 32);
        acc8[j] = v;
    }
    if (active && l < 8) {                            // group 0 writes h row
        #pragma unroll
        for (int j = 0; j < 8; ++j)
            hbuf[wave][lc * 8 + j] = fmaxf(acc8[j] * di + b1[lc * 8 + j], 0.f);
    }
    __syncthreads();                                  // covers w2s + hbuf
    if (active) {
        if (l < CLS) {
            float o = 0.f;
            const float* hr = hbuf[wave];
            #pragma unroll 16
            for (int k = 0; k < HID; ++k) o += hr[k] * w2s[k * CLS + l];
            hws[(size_t)wv * HID + l] = f2bf(o * di);
        } else {
            hws[(size_t)wv * HID + l] = 0;            // zero-pad ch 40..63
        }
    }
}

// ---------- layer 2 gather fused with finalize ------------------------------
// hws rows padded to 64 bf16 (128B) -> identical 8x8 load structure.
// Stores PRE-NORMALIZED bf16 rows (raw * rnorm): edge dot == cosine directly.
__global__ void gather2_fin_kernel(const int* __restrict__ rowptr,
                                   const ushort_t* __restrict__ csr,
                                   const ushort_t* __restrict__ hws,
                                   const float* __restrict__ dinv,
                                   const float* __restrict__ b2,
                                   float* __restrict__ xout, float* __restrict__ lsm,
                                   float* __restrict__ sm, ushort_t* __restrict__ xnb,
                                   int n) {
    int tid = threadIdx.x;
    int wv  = (blockIdx.x * blockDim.x + tid) >> 6;
    if (wv >= n) return;
    int l  = tid & 63;
    int g  = l >> 3;
    int lc = l & 7;                                   // channels lc*8..lc*8+7
    int beg = rowptr[wv], endp = rowptr[wv + 1];
    float di = dinv[wv];
    float acc8[8];
    #pragma unroll
    for (int j = 0; j < 8; ++j) acc8[j] = 0.f;
    if (l < 8) {                                      // self-loop term
        uint4 sv = *(const uint4*)(hws + (size_t)wv * HID + lc * 8);
        acc8[0] = blo(sv.x); acc8[1] = bhi(sv.x);
        acc8[2] = blo(sv.y); acc8[3] = bhi(sv.y);
        acc8[4] = blo(sv.z); acc8[5] = bhi(sv.z);
        acc8[6] = blo(sv.w); acc8[7] = bhi(sv.w);
    }
    for (int ch = beg; ch < endp; ch += 32) {
        #pragma unroll
        for (int k = 0; k < 4; ++k) {
            int e = ch + k * 8 + g;
            bool val = e < endp;
            int ec = val ? e : (endp - 1);
            int s = (int)csr[ec];
            uint4 p = *(const uint4*)(hws + (size_t)s * HID + lc * 8);
            if (!val) { p.x = 0u; p.y = 0u; p.z = 0u; p.w = 0u; }
            acc8[0] += blo(p.x); acc8[1] += bhi(p.x);
            acc8[2] += blo(p.y); acc8[3] += bhi(p.y);
            acc8[4] += blo(p.z); acc8[5] += bhi(p.z);
            acc8[6] += blo(p.w); acc8[7] += bhi(p.w);
        }
    }
    #pragma unroll
    for (int j = 0; j < 8; ++j) {
        float v = acc8[j];
        v += __shfl_xor(v, 8);
        v += __shfl_xor(v, 16);
        v += __shfl_xor(v, 32);
        acc8[j] = v;
    }
    bool cgv = lc < 5;                                // 40 = 5 groups x 8 ch
    float raw[8];
    if (cgv) {
        #pragma unroll
        for (int j = 0; j < 8; ++j) raw[j] = acc8[j] * di + b2[lc * 8 + j];
    } else {
        #pragma unroll
        for (int j = 0; j < 8; ++j) raw[j] = 0.f;
    }
    float mx = -3.0e38f;
    if (cgv) {
        #pragma unroll
        for (int j = 0; j < 8; ++j) mx = fmaxf(mx, raw[j]);
    }
    mx = fmaxf(mx, __shfl_xor(mx, 1));
    mx = fmaxf(mx, __shfl_xor(mx, 2));
    mx = fmaxf(mx, __shfl_xor(mx, 4));
    float ex[8];
    float ls = 0.f;
    if (cgv) {
        #pragma unroll
        for (int j = 0; j < 8; ++j) { ex[j] = __expf(raw[j] - mx); ls += ex[j]; }
    } else {
        #pragma unroll
        for (int j = 0; j < 8; ++j) ex[j] = 0.f;
    }
    ls += __shfl_xor(ls, 1);
    ls += __shfl_xor(ls, 2);
    ls += __shfl_xor(ls, 4);
    float sq = 0.f;
    if (cgv) {
        #pragma unroll
        for (int j = 0; j < 8; ++j) sq += raw[j] * raw[j];
    }
    sq += __shfl_xor(sq, 1);
    sq += __shfl_xor(sq, 2);
    sq += __shfl_xor(sq, 4);
    float rn = 1.0f / fmaxf(sqrtf(sq), EPS);          // all lanes have full sq
    if (l < 5) {                                      // lanes 0..4 write row
        size_t fb = (size_t)wv * CLS + l * 8;
        *(float4*)(xout + fb)     = make_float4(raw[0], raw[1], raw[2], raw[3]);
        *(float4*)(xout + fb + 4) = make_float4(raw[4], raw[5], raw[6], raw[7]);
        float lse = mx + __logf(ls);
        *(float4*)(lsm + fb)     = make_float4(raw[0] - lse, raw[1] - lse, raw[2] - lse, raw[3] - lse);
        *(float4*)(lsm + fb + 4) = make_float4(raw[4] - lse, raw[5] - lse, raw[6] - lse, raw[7] - lse);
        float inv = 1.0f / ls;
        *(float4*)(sm + fb)     = make_float4(ex[0] * inv, ex[1] * inv, ex[2] * inv, ex[3] * inv);
        *(float4*)(sm + fb + 4) = make_float4(ex[4] * inv, ex[5] * inv, ex[6] * inv, ex[7] * inv);
        uint4 pb;                                     // normalized bf16 row
        pb.x = (uint_t)f2bf(raw[0] * rn) | ((uint_t)f2bf(raw[1] * rn) << 16);
        pb.y = (uint_t)f2bf(raw[2] * rn) | ((uint_t)f2bf(raw[3] * rn) << 16);
        pb.z = (uint_t)f2bf(raw[4] * rn) | ((uint_t)f2bf(raw[5] * rn) << 16);
        pb.w = (uint_t)f2bf(raw[6] * rn) | ((uint_t)f2bf(raw[7] * rn) << 16);
        *(uint4*)(xnb + fb) = pb;                     // byte off = wv*80+l*16
    }
}

// ------------- per-edge cosine dissimilarity + gnn_edge ---------------------
// 8 lanes per edge, 32 edges (4 batches) per wave: all 4 pair loads then all
// 8 row gathers issue before any reduction -> 4-deep load ILP hides latency.
// Rows pre-normalized -> dot = cosine.
__global__ void edge_kernel(const uint_t* __restrict__ pair,
                            const float* __restrict__ ew, const ushort_t* __restrict__ xnb,
                            float* __restrict__ cos_out, float* __restrict__ gnn_out, int E) {
    int tid = threadIdx.x;
    int wid = (blockIdx.x * blockDim.x + tid) >> 6;   // global wave id
    int l = tid & 63;
    int g = l >> 3;                                   // edge slot 0..7 in batch
    int j = l & 7;                                    // 16B chunk slot
    int e0 = wid * 32;                                // 32 edges per wave
    if (e0 >= E) return;
    uint_t u[4];
    #pragma unroll
    for (int k = 0; k < 4; ++k) {                     // 4 independent pair loads
        int e = e0 + k * 8 + g;
        u[k] = (e < E) ? pair[e] : pair[E - 1];       // clamp: safe row, store guarded
    }
    uint4 av[4], bv[4];
    #pragma unroll
    for (int k = 0; k < 4; ++k) {                     // 8 independent gathers
        int s = (int)(u[k] & 0xffffu);
        int d = (int)(u[k] >> 16);
        if (j < 5) {                                  // rows are 80B = 5 x 16B
            av[k] = *(const uint4*)(xnb + (size_t)s * CLS + j * 8);
            bv[k] = *(const uint4*)(xnb + (size_t)d * CLS + j * 8);
        }
    }
    #pragma unroll
    for (int k = 0; k < 4; ++k) {                     // reduce + store per batch
        float part = 0.f;
        if (j < 5) part = dot_u4(av[k], bv[k]);
        part += __shfl_xor(part, 1);
        part += __shfl_xor(part, 2);
        part += __shfl_xor(part, 4);
        int e = e0 + k * 8 + g;
        if (j == 0 && e < E) {                        // 8 leaders: 32B coalesced
            cos_out[e] = 1.0f - part;
            gnn_out[e] = (ew[e] > 0.5f) ? 1.0f : -1.0f;
        }
    }
}

// ---------------------------------------------------------------------------
extern "C" void kernel_launch(void* const* d_in, const int* in_sizes, int n_in,
                              void* d_out, int out_size, void* d_ws, size_t ws_size,
                              hipStream_t stream) {
    const float* x   = (const float*)d_in[0];
    const void*  ei  = d_in[1];
    const float* ew  = (const float*)d_in[2];
    const float* W1  = (const float*)d_in[3];
    const float* b1  = (const float*)d_in[4];
    const float* W2  = (const float*)d_in[5];
    const float* b2  = (const float*)d_in[6];

    const int n = in_sizes[0] / F_IN;        // 50000
    const int E = in_sizes[2];               // 1600000

    // output segments (return order)
    float* lsm  = (float*)d_out;                                   // [n*CLS]
    float* xout = lsm + (size_t)n * CLS;                           // [n*CLS]
    float* cosO = xout + (size_t)n * CLS;                          // [E]
    float* gnnO = cosO + E;                                        // [E]
    float* smO  = gnnO + E;                                        // [n*CLS]

    // workspace layout (256B aligned)
    char* w = (char*)d_ws;
    auto alloc = [&](size_t bytes) {
        char* p = w;
        w += (bytes + 255) & ~(size_t)255;
        return p;
    };
    const int NBLK  = (E + EPB - 1) / EPB;   // 196 hist/scatter blocks
    const int NBUCK = (n + 255) / 256;       // 196 buckets (dst>>8)

    uint_t*   pair   = (uint_t*)  alloc((size_t)E * 4);
    uint_t*   bkt    = (uint_t*)  alloc((size_t)E * 4);
    ushort_t* csr16  = (ushort_t*)alloc((size_t)E * 2);
    int*      ghist  = (int*)     alloc((size_t)NBLK * 256 * 4);
    int*      btot   = (int*)     alloc(256 * 4);
    int*      bbase  = (int*)     alloc(257 * 4);
    int*      rowptr = (int*)     alloc(((size_t)n + 1) * 4);
    float*    dinv   = (float*)   alloc((size_t)n * 4);
    ushort_t* xws    = (ushort_t*)alloc((size_t)n * HID * 2);
    ushort_t* hws    = (ushort_t*)alloc((size_t)n * HID * 2);   // padded to 64 ch
    ushort_t* xnb    = (ushort_t*)alloc((size_t)n * CLS * 2);   // normalized rows
    ushort_t* W1s    = (ushort_t*)alloc((size_t)4 * 8 * 64 * 8 * 2);   // 32 KB
    int*      flag   = (int*)     alloc(64);

    detect_kernel<<<1, 64, 0, stream>>>((const int*)ei, flag);
    convert_w1_kernel<<<8, 256, 0, stream>>>(W1, W1s);
    build_hist_kernel<<<NBLK, 256, 0, stream>>>(ei, flag, pair, ghist, E);
    scan_cols_kernel<<<256, 64, 0, stream>>>(ghist, btot, NBLK);
    scan_base_kernel<<<1, 256, 0, stream>>>(btot, bbase);
    scatter_buckets_kernel<<<NBLK, 256, 0, stream>>>(pair, ghist, bbase, bkt, E);
    bucket_csr_kernel<<<NBUCK, 256, 0, stream>>>(bkt, bbase, csr16, rowptr, dinv, n, E, NBUCK);
    gemm1_mfma_kernel<<<(n + 15) / 16, 256, 0, stream>>>(x, W1s, dinv, xws, n);
    gather1_gemm2_kernel<<<((size_t)n * 64 + 255) / 256, 256, 0, stream>>>(rowptr, csr16, xws, dinv,
                                                                           b1, W2, hws, n);
    gather2_fin_kernel<<<((size_t)n * 64 + 255) / 256, 256, 0, stream>>>(rowptr, csr16, hws, dinv, b2,
                                                                         xout, lsm, smO, xnb, n);
    edge_kernel<<<((size_t)((E + 31) / 32) * 64 + 255) / 256, 256, 0, stream>>>(pair, ew, xnb, cosO, gnnO, E);
}

// Round 10
// 281.799 us; speedup vs baseline: 1.4936x; 1.0152x over previous
//
#include <hip/hip_runtime.h>
#include <hip/hip_bf16.h>

#define F_IN 256
#define HID  64
#define CLS  40
#define EPS  1e-8f
#define XS_STRIDE 264   // halfwords per LDS x-tile row: 2-way max bank aliasing (free)
#define H2_STRIDE 72    // halfwords per LDS h-tile row in gemm2
#define EPB  8192       // edges per block in hist/scatter passes (256 thr x 32)

typedef unsigned short ushort_t;
typedef unsigned int   uint_t;
typedef __attribute__((ext_vector_type(8))) short bf16x8;
typedef __attribute__((ext_vector_type(4))) float f32x4;

__device__ __forceinline__ float bf2f(ushort_t u) {
    union { uint_t i; float f; } v; v.i = ((uint_t)u) << 16; return v.f;
}
__device__ __forceinline__ ushort_t f2bf(float f) {
    union { float f; uint_t i; } v; v.f = f;
    uint_t r = v.i + 0x7fff + ((v.i >> 16) & 1);          // RNE
    return (ushort_t)(r >> 16);
}
__device__ __forceinline__ float blo(uint_t p) {
    union { uint_t i; float f; } v; v.i = p << 16; return v.f;
}
__device__ __forceinline__ float bhi(uint_t p) {
    union { uint_t i; float f; } v; v.i = p & 0xffff0000u; return v.f;
}
__device__ __forceinline__ float dot_u4(uint4 a, uint4 b) {
    return blo(a.x) * blo(b.x) + bhi(a.x) * bhi(b.x)
         + blo(a.y) * blo(b.y) + bhi(a.y) * bhi(b.y)
         + blo(a.z) * blo(b.z) + bhi(a.z) * bhi(b.z)
         + blo(a.w) * blo(b.w) + bhi(a.w) * bhi(b.w);
}

// -------------------- dtype detection (int64 vs int32 edge_index) -----------
__global__ void detect_kernel(const int* __restrict__ raw, int* __restrict__ flag) {
    int c = threadIdx.x;                  // one wave
    int w = raw[2 * c + 1];               // odd int32 words
    unsigned long long b = __ballot(w != 0);
    if (c == 0) *flag = (b == 0ULL) ? 1 : 0;   // all zero -> int64 layout
}

// ---- pass 1: pair packing + per-block bucket histogram (dst>>8) ------------
__global__ void build_hist_kernel(const void* __restrict__ raw, const int* __restrict__ flag,
                                  uint_t* __restrict__ pair, int* __restrict__ ghist, int E) {
    __shared__ int lhist[256];
    int tid = threadIdx.x;
    lhist[tid] = 0;
    __syncthreads();
    int base = blockIdx.x * EPB;
    if (*flag) {
        const long long* r = (const long long*)raw;
        for (int it = 0; it < EPB / 1024; ++it) {        // 4 edges/thread/iter
            int e = base + (it * 256 + tid) * 4;
            if (e + 4 <= E) {
                ulonglong2 a0 = *(const ulonglong2*)(r + e);
                ulonglong2 a1 = *(const ulonglong2*)(r + e + 2);
                ulonglong2 b0 = *(const ulonglong2*)(r + E + e);
                ulonglong2 b1 = *(const ulonglong2*)(r + E + e + 2);
                uint_t d0 = (uint_t)b0.x, d1 = (uint_t)b0.y;
                uint_t d2 = (uint_t)b1.x, d3 = (uint_t)b1.y;
                uint4 p;
                p.x = (d0 << 16) | (uint_t)a0.x;
                p.y = (d1 << 16) | (uint_t)a0.y;
                p.z = (d2 << 16) | (uint_t)a1.x;
                p.w = (d3 << 16) | (uint_t)a1.y;
                *(uint4*)(pair + e) = p;
                atomicAdd(&lhist[d0 >> 8], 1);
                atomicAdd(&lhist[d1 >> 8], 1);
                atomicAdd(&lhist[d2 >> 8], 1);
                atomicAdd(&lhist[d3 >> 8], 1);
            } else {
                for (int k = 0; k < 4; ++k) {
                    int ee = e + k;
                    if (ee < E) {
                        uint_t s = (uint_t)r[ee];
                        uint_t d = (uint_t)r[E + ee];
                        pair[ee] = (d << 16) | s;
                        atomicAdd(&lhist[d >> 8], 1);
                    }
                }
            }
        }
    } else {
        const int* r = (const int*)raw;
        for (int it = 0; it < EPB / 1024; ++it) {        // 4 edges/thread/iter
            int e = base + (it * 256 + tid) * 4;
            if (e + 4 <= E) {
                int4 a = *(const int4*)(r + e);
                int4 b = *(const int4*)(r + E + e);
                uint_t d0 = (uint_t)b.x, d1 = (uint_t)b.y;
                uint_t d2 = (uint_t)b.z, d3 = (uint_t)b.w;
                uint4 p;
                p.x = (d0 << 16) | (uint_t)a.x;
                p.y = (d1 << 16) | (uint_t)a.y;
                p.z = (d2 << 16) | (uint_t)a.z;
                p.w = (d3 << 16) | (uint_t)a.w;
                *(uint4*)(pair + e) = p;
                atomicAdd(&lhist[d0 >> 8], 1);
                atomicAdd(&lhist[d1 >> 8], 1);
                atomicAdd(&lhist[d2 >> 8], 1);
                atomicAdd(&lhist[d3 >> 8], 1);
            } else {
                for (int k = 0; k < 4; ++k) {
                    int ee = e + k;
                    if (ee < E) {
                        uint_t s = (uint_t)r[ee];
                        uint_t d = (uint_t)r[E + ee];
                        pair[ee] = (d << 16) | s;
                        atomicAdd(&lhist[d >> 8], 1);
                    }
                }
            }
        }
    }
    __syncthreads();
    ghist[blockIdx.x * 256 + tid] = lhist[tid];
}

// ---- pass 2a: PARALLEL column scan — one wave per bucket -------------------
__global__ void scan_cols_kernel(int* __restrict__ ghist, int* __restrict__ btot,
                                 int NBLK) {
    int k    = blockIdx.x;                 // bucket 0..255
    int lane = threadIdx.x;                // 0..63
    int carry = 0;
    for (int b0 = 0; b0 < NBLK; b0 += 64) {
        int b = b0 + lane;
        int v = (b < NBLK) ? ghist[b * 256 + k] : 0;
        int x = v;
        #pragma unroll
        for (int o = 1; o < 64; o <<= 1) {
            int t = __shfl_up(x, o);
            if (lane >= o) x += t;
        }
        if (b < NBLK) ghist[b * 256 + k] = carry + x - v;   // exclusive offset
        carry += __shfl(x, 63);            // batch total
    }
    if (lane == 0) btot[k] = carry;        // bucket total
}

// ---- pass 2b (1 block): exclusive scan of bucket totals -> bucket bases ----
__global__ void scan_base_kernel(const int* __restrict__ btot, int* __restrict__ bbase) {
    __shared__ int s[256];
    int k = threadIdx.x;
    int v = btot[k];
    int x = v;
    s[k] = x;
    __syncthreads();
    #pragma unroll
    for (int o = 1; o < 256; o <<= 1) {
        int t = (k >= o) ? s[k - o] : 0;
        __syncthreads();
        x += t;
        s[k] = x;
        __syncthreads();
    }
    bbase[k] = x - v;                      // exclusive bucket base
    if (k == 255) bbase[256] = x;          // == E
}

// ---- pass 3: scatter edges into bucket regions (LDS cursors only) ----------
__global__ void scatter_buckets_kernel(const uint_t* __restrict__ pair,
                                       const int* __restrict__ ghist,
                                       const int* __restrict__ bbase,
                                       uint_t* __restrict__ bkt, int E) {
    __shared__ int cursor[256];
    int tid = threadIdx.x;
    cursor[tid] = ghist[blockIdx.x * 256 + tid] + bbase[tid];
    __syncthreads();
    int base = blockIdx.x * EPB;
    for (int it = 0; it < EPB / 256; ++it) {
        int e = base + it * 256 + tid;
        if (e < E) {
            uint_t u = pair[e];
            int pos = atomicAdd(&cursor[u >> 24], 1);   // LDS atomic, returns rank
            bkt[pos] = u;
        }
    }
}

// ---- pass 4: one block per bucket -> deg/rowptr/dinv + sorted csr16 --------
__global__ void bucket_csr_kernel(const uint_t* __restrict__ bkt,
                                  const int* __restrict__ bbase,
                                  ushort_t* __restrict__ csr, int* __restrict__ rowptr,
                                  float* __restrict__ dinv, int n, int E, int NBUCK) {
    __shared__ int lhist[256];
    __shared__ int lscan[256];
    __shared__ int cursor[256];
    int tid = threadIdx.x;
    int kb  = blockIdx.x;
    int base = bbase[kb];
    int cnt  = bbase[kb + 1] - base;
    lhist[tid] = 0;
    __syncthreads();
    for (int i = tid; i < cnt; i += 256) {            // pass A: exact degrees
        uint_t u = bkt[base + i];
        atomicAdd(&lhist[(u >> 16) & 255], 1);
    }
    __syncthreads();
    int v = lhist[tid];                        // degree of node kb*256+tid (no self-loop)
    int x = v;
    lscan[tid] = x;
    __syncthreads();
    #pragma unroll
    for (int o = 1; o < 256; o <<= 1) {
        int t = (tid >= o) ? lscan[tid - o] : 0;
        __syncthreads();
        x += t;
        lscan[tid] = x;
        __syncthreads();
    }
    int excl = x - v;                          // exclusive scan within bucket
    int node = kb * 256 + tid;
    if (node < n) {
        rowptr[node] = base + excl;
        dinv[node]   = rsqrtf((float)(v + 1)); // +1 self-loop
    }
    cursor[tid] = base + excl;
    if (kb == NBUCK - 1 && tid == 0) rowptr[n] = E;
    __syncthreads();
    for (int i = tid; i < cnt; i += 256) {            // pass B: place src
        uint_t u = bkt[base + i];                     // L2 hit (just touched)
        int pos = atomicAdd(&cursor[(u >> 16) & 255], 1);   // LDS atomic
        csr[pos] = (ushort_t)(u & 0xffffu);    // 2B scatter, block-local region
    }
}

// ---- W1 -> bf16, pre-swizzled into MFMA B-fragment order -------------------
__global__ void convert_w1_kernel(const float* __restrict__ W1, ushort_t* __restrict__ W1s) {
    int t = blockIdx.x * blockDim.x + threadIdx.x;   // 2048 triples
    if (t >= 4 * 8 * 64) return;
    int lane = t & 63;
    int kk   = (t >> 6) & 7;
    int nt   = t >> 9;
    int col  = nt * 16 + (lane & 15);
    int k0   = kk * 32 + (lane >> 4) * 8;
    ushort_t v[8];
    #pragma unroll
    for (int j = 0; j < 8; ++j) v[j] = f2bf(W1[(size_t)(k0 + j) * HID + col]);
    uint4 p;
    p.x = (uint_t)v[0] | ((uint_t)v[1] << 16);
    p.y = (uint_t)v[2] | ((uint_t)v[3] << 16);
    p.z = (uint_t)v[4] | ((uint_t)v[5] << 16);
    p.w = (uint_t)v[6] | ((uint_t)v[7] << 16);
    *(uint4*)(W1s + (size_t)t * 8) = p;
}

// ---- W2 -> bf16 MFMA B-fragments: 4 N-tiles x 2 kk; cols >= 40 zero-padded -
__global__ void convert_w2_kernel(const float* __restrict__ W2, ushort_t* __restrict__ W2s) {
    int t = blockIdx.x * blockDim.x + threadIdx.x;   // 512 triples
    if (t >= 4 * 2 * 64) return;
    int lane = t & 63;
    int kk   = (t >> 6) & 1;
    int nt   = t >> 7;
    int col  = nt * 16 + (lane & 15);
    int k0   = kk * 32 + (lane >> 4) * 8;
    ushort_t v[8];
    #pragma unroll
    for (int j = 0; j < 8; ++j)
        v[j] = (col < CLS) ? f2bf(W2[(size_t)(k0 + j) * CLS + col]) : (ushort_t)0;
    uint4 p;
    p.x = (uint_t)v[0] | ((uint_t)v[1] << 16);
    p.y = (uint_t)v[2] | ((uint_t)v[3] << 16);
    p.z = (uint_t)v[4] | ((uint_t)v[5] << 16);
    p.w = (uint_t)v[6] | ((uint_t)v[7] << 16);
    *(uint4*)(W2s + (size_t)t * 8) = p;
}

// ------- layer 1 GEMM on MFMA: xws = bf16((x @ W1) * dinv[node]) ------------
__global__ void gemm1_mfma_kernel(const float* __restrict__ x,
                                  const ushort_t* __restrict__ W1s,
                                  const float* __restrict__ dinv,
                                  ushort_t* __restrict__ xws, int n) {
    __shared__ ushort_t xs[16 * XS_STRIDE];           // 8448 B bf16 x-tile
    int node0 = blockIdx.x * 16;
    int tid = threadIdx.x;
    for (int i = tid; i < 16 * 64; i += 256) {        // stage x tile -> bf16 LDS
        int r  = i >> 6;
        int c4 = (i & 63) << 2;
        int node = node0 + r;
        float4 v = (node < n) ? *(const float4*)(x + (size_t)node * F_IN + c4)
                              : make_float4(0.f, 0.f, 0.f, 0.f);
        ushort4 b;
        b.x = f2bf(v.x); b.y = f2bf(v.y); b.z = f2bf(v.z); b.w = f2bf(v.w);
        *(ushort4*)(&xs[r * XS_STRIDE + c4]) = b;     // 8B-aligned ds_write_b64
    }
    __syncthreads();
    int wave = tid >> 6;                              // N-tile index 0..3
    int lane = tid & 63;
    int m    = lane & 15;
    int q    = lane >> 4;
    f32x4 acc = {0.f, 0.f, 0.f, 0.f};
    #pragma unroll
    for (int kk = 0; kk < 8; ++kk) {                  // K = 8 x 32
        bf16x8 a = *(const bf16x8*)(&xs[m * XS_STRIDE + kk * 32 + q * 8]);
        bf16x8 b = *(const bf16x8*)(W1s + (((size_t)wave * 8 + kk) * 64 + lane) * 8);
        acc = __builtin_amdgcn_mfma_f32_16x16x32_bf16(a, b, acc, 0, 0, 0);
    }
    int ch = wave * 16 + m;                           // C/D: col=lane&15, row=q*4+r
    #pragma unroll
    for (int r = 0; r < 4; ++r) {
        int node = node0 + q * 4 + r;
        if (node < n)
            xws[(size_t)node * HID + ch] = f2bf(acc[r] * dinv[node]);
    }
}

// ---- gather1: h = bf16(relu(dinv*(sum)+b1)) — pure gather, no LDS/barrier --
// one wave per node; 8 lane-groups x 16B = one dwordx4 fetches 8 edge-rows.
// acc8[8] per lane; xor-reduce (^8,^16,^32); group-0 lanes write the h row.
__global__ void gather1_kernel(const int* __restrict__ rowptr,
                               const ushort_t* __restrict__ csr,
                               const ushort_t* __restrict__ xws,
                               const float* __restrict__ dinv,
                               const float* __restrict__ b1,
                               ushort_t* __restrict__ h, int n) {
    int tid = threadIdx.x;
    int wv  = (blockIdx.x * blockDim.x + tid) >> 6;
    if (wv >= n) return;
    int l  = tid & 63;
    int g  = l >> 3;                                  // row-group 0..7
    int lc = l & 7;                                   // channel-group (8 ch each)
    int beg = rowptr[wv], endp = rowptr[wv + 1];
    float di = dinv[wv];
    float acc8[8];
    #pragma unroll
    for (int j = 0; j < 8; ++j) acc8[j] = 0.f;
    if (l < 8) {                                      // self-loop: group 0 only
        uint4 sv = *(const uint4*)(xws + (size_t)wv * HID + lc * 8);
        acc8[0] = blo(sv.x); acc8[1] = bhi(sv.x);
        acc8[2] = blo(sv.y); acc8[3] = bhi(sv.y);
        acc8[4] = blo(sv.z); acc8[5] = bhi(sv.z);
        acc8[6] = blo(sv.w); acc8[7] = bhi(sv.w);
    }
    for (int ch = beg; ch < endp; ch += 32) {         // 32 edges per iteration
        #pragma unroll
        for (int k = 0; k < 4; ++k) {                 // 4 independent 8-row loads
            int e = ch + k * 8 + g;
            bool val = e < endp;
            int ec = val ? e : (endp - 1);            // clamp, mask value below
            int s = (int)csr[ec];                     // 64 lanes -> one 16B line
            uint4 p = *(const uint4*)(xws + (size_t)s * HID + lc * 8);
            if (!val) { p.x = 0u; p.y = 0u; p.z = 0u; p.w = 0u; }
            acc8[0] += blo(p.x); acc8[1] += bhi(p.x);
            acc8[2] += blo(p.y); acc8[3] += bhi(p.y);
            acc8[4] += blo(p.z); acc8[5] += bhi(p.z);
            acc8[6] += blo(p.w); acc8[7] += bhi(p.w);
        }
    }
    #pragma unroll
    for (int j = 0; j < 8; ++j) {                     // sum the 8 row-groups
        float v = acc8[j];
        v += __shfl_xor(v, 8);
        v += __shfl_xor(v, 16);
        v += __shfl_xor(v, 32);
        acc8[j] = v;
    }
    if (l < 8) {                                      // group 0 writes h row
        float4 bb0 = *(const float4*)(b1 + lc * 8);
        float4 bb1 = *(const float4*)(b1 + lc * 8 + 4);
        float h0 = fmaxf(acc8[0] * di + bb0.x, 0.f);
        float h1 = fmaxf(acc8[1] * di + bb0.y, 0.f);
        float h2 = fmaxf(acc8[2] * di + bb0.z, 0.f);
        float h3 = fmaxf(acc8[3] * di + bb0.w, 0.f);
        float h4 = fmaxf(acc8[4] * di + bb1.x, 0.f);
        float h5 = fmaxf(acc8[5] * di + bb1.y, 0.f);
        float h6 = fmaxf(acc8[6] * di + bb1.z, 0.f);
        float h7 = fmaxf(acc8[7] * di + bb1.w, 0.f);
        uint4 pb;
        pb.x = (uint_t)f2bf(h0) | ((uint_t)f2bf(h1) << 16);
        pb.y = (uint_t)f2bf(h2) | ((uint_t)f2bf(h3) << 16);
        pb.z = (uint_t)f2bf(h4) | ((uint_t)f2bf(h5) << 16);
        pb.w = (uint_t)f2bf(h6) | ((uint_t)f2bf(h7) << 16);
        *(uint4*)(h + (size_t)wv * HID + lc * 8) = pb;
    }
}

// ------- layer 2 GEMM on MFMA: hws = bf16((h @ W2) * dinv[node]) ------------
// 16 nodes/block, K = 2 x 32, wave w owns N-tile w; cols 40..63 are zero
// (W2s zero-padded) so hws stays 64-ch padded for gather2's 8x8 loads.
__global__ void gemm2_mfma_kernel(const ushort_t* __restrict__ h,
                                  const ushort_t* __restrict__ W2s,
                                  const float* __restrict__ dinv,
                                  ushort_t* __restrict__ hws, int n) {
    __shared__ ushort_t hs[16 * H2_STRIDE];           // 2304 B bf16 h-tile
    int node0 = blockIdx.x * 16;
    int tid = threadIdx.x;
    {
        int r  = tid >> 4;                            // 16 rows
        int c4 = (tid & 15) << 2;                     // 16 chunks of 4 halfwords
        int node = node0 + r;
        ushort4 v = make_ushort4(0, 0, 0, 0);
        if (node < n) v = *(const ushort4*)(h + (size_t)node * HID + c4);
        *(ushort4*)(&hs[r * H2_STRIDE + c4]) = v;
    }
    __syncthreads();
    int wave = tid >> 6;                              // N-tile index 0..3
    int lane = tid & 63;
    int m    = lane & 15;
    int q    = lane >> 4;
    f32x4 acc = {0.f, 0.f, 0.f, 0.f};
    #pragma unroll
    for (int kk = 0; kk < 2; ++kk) {                  // K = 2 x 32
        bf16x8 a = *(const bf16x8*)(&hs[m * H2_STRIDE + kk * 32 + q * 8]);
        bf16x8 b = *(const bf16x8*)(W2s + (((size_t)wave * 2 + kk) * 64 + lane) * 8);
        acc = __builtin_amdgcn_mfma_f32_16x16x32_bf16(a, b, acc, 0, 0, 0);
    }
    int ch = wave * 16 + m;                           // C/D: col=lane&15, row=q*4+r
    #pragma unroll
    for (int r = 0; r < 4; ++r) {
        int node = node0 + q * 4 + r;
        if (node < n)
            hws[(size_t)node * HID + ch] = f2bf(acc[r] * dinv[node]);
    }
}

// ---------- layer 2 gather fused with finalize ------------------------------
// hws rows padded to 64 bf16 (128B) -> identical 8x8 load structure.
// Stores PRE-NORMALIZED bf16 rows (raw * rnorm): edge dot == cosine directly.
__global__ void gather2_fin_kernel(const int* __restrict__ rowptr,
                                   const ushort_t* __restrict__ csr,
                                   const ushort_t* __restrict__ hws,
                                   const float* __restrict__ dinv,
                                   const float* __restrict__ b2,
                                   float* __restrict__ xout, float* __restrict__ lsm,
                                   float* __restrict__ sm, ushort_t* __restrict__ xnb,
                                   int n) {
    int tid = threadIdx.x;
    int wv  = (blockIdx.x * blockDim.x + tid) >> 6;
    if (wv >= n) return;
    int l  = tid & 63;
    int g  = l >> 3;
    int lc = l & 7;                                   // channels lc*8..lc*8+7
    int beg = rowptr[wv], endp = rowptr[wv + 1];
    float di = dinv[wv];
    float acc8[8];
    #pragma unroll
    for (int j = 0; j < 8; ++j) acc8[j] = 0.f;
    if (l < 8) {                                      // self-loop term
        uint4 sv = *(const uint4*)(hws + (size_t)wv * HID + lc * 8);
        acc8[0] = blo(sv.x); acc8[1] = bhi(sv.x);
        acc8[2] = blo(sv.y); acc8[3] = bhi(sv.y);
        acc8[4] = blo(sv.z); acc8[5] = bhi(sv.z);
        acc8[6] = blo(sv.w); acc8[7] = bhi(sv.w);
    }
    for (int ch = beg; ch < endp; ch += 32) {
        #pragma unroll
        for (int k = 0; k < 4; ++k) {
            int e = ch + k * 8 + g;
            bool val = e < endp;
            int ec = val ? e : (endp - 1);
            int s = (int)csr[ec];
            uint4 p = *(const uint4*)(hws + (size_t)s * HID + lc * 8);
            if (!val) { p.x = 0u; p.y = 0u; p.z = 0u; p.w = 0u; }
            acc8[0] += blo(p.x); acc8[1] += bhi(p.x);
            acc8[2] += blo(p.y); acc8[3] += bhi(p.y);
            acc8[4] += blo(p.z); acc8[5] += bhi(p.z);
            acc8[6] += blo(p.w); acc8[7] += bhi(p.w);
        }
    }
    #pragma unroll
    for (int j = 0; j < 8; ++j) {
        float v = acc8[j];
        v += __shfl_xor(v, 8);
        v += __shfl_xor(v, 16);
        v += __shfl_xor(v, 32);
        acc8[j] = v;
    }
    bool cgv = lc < 5;                                // 40 = 5 groups x 8 ch
    float raw[8];
    if (cgv) {
        #pragma unroll
        for (int j = 0; j < 8; ++j) raw[j] = acc8[j] * di + b2[lc * 8 + j];
    } else {
        #pragma unroll
        for (int j = 0; j < 8; ++j) raw[j] = 0.f;
    }
    float mx = -3.0e38f;
    if (cgv) {
        #pragma unroll
        for (int j = 0; j < 8; ++j) mx = fmaxf(mx, raw[j]);
    }
    mx = fmaxf(mx, __shfl_xor(mx, 1));
    mx = fmaxf(mx, __shfl_xor(mx, 2));
    mx = fmaxf(mx, __shfl_xor(mx, 4));
    float ex[8];
    float ls = 0.f;
    if (cgv) {
        #pragma unroll
        for (int j = 0; j < 8; ++j) { ex[j] = __expf(raw[j] - mx); ls += ex[j]; }
    } else {
        #pragma unroll
        for (int j = 0; j < 8; ++j) ex[j] = 0.f;
    }
    ls += __shfl_xor(ls, 1);
    ls += __shfl_xor(ls, 2);
    ls += __shfl_xor(ls, 4);
    float sq = 0.f;
    if (cgv) {
        #pragma unroll
        for (int j = 0; j < 8; ++j) sq += raw[j] * raw[j];
    }
    sq += __shfl_xor(sq, 1);
    sq += __shfl_xor(sq, 2);
    sq += __shfl_xor(sq, 4);
    float rn = 1.0f / fmaxf(sqrtf(sq), EPS);          // all lanes have full sq
    if (l < 5) {                                      // lanes 0..4 write row
        size_t fb = (size_t)wv * CLS + l * 8;
        *(float4*)(xout + fb)     = make_float4(raw[0], raw[1], raw[2], raw[3]);
        *(float4*)(xout + fb + 4) = make_float4(raw[4], raw[5], raw[6], raw[7]);
        float lse = mx + __logf(ls);
        *(float4*)(lsm + fb)     = make_float4(raw[0] - lse, raw[1] - lse, raw[2] - lse, raw[3] - lse);
        *(float4*)(lsm + fb + 4) = make_float4(raw[4] - lse, raw[5] - lse, raw[6] - lse, raw[7] - lse);
        float inv = 1.0f / ls;
        *(float4*)(sm + fb)     = make_float4(ex[0] * inv, ex[1] * inv, ex[2] * inv, ex[3] * inv);
        *(float4*)(sm + fb + 4) = make_float4(ex[4] * inv, ex[5] * inv, ex[6] * inv, ex[7] * inv);
        uint4 pb;                                     // normalized bf16 row
        pb.x = (uint_t)f2bf(raw[0] * rn) | ((uint_t)f2bf(raw[1] * rn) << 16);
        pb.y = (uint_t)f2bf(raw[2] * rn) | ((uint_t)f2bf(raw[3] * rn) << 16);
        pb.z = (uint_t)f2bf(raw[4] * rn) | ((uint_t)f2bf(raw[5] * rn) << 16);
        pb.w = (uint_t)f2bf(raw[6] * rn) | ((uint_t)f2bf(raw[7] * rn) << 16);
        *(uint4*)(xnb + fb) = pb;                     // byte off = wv*80+l*16
    }
}

// ------------- per-edge cosine dissimilarity + gnn_edge ---------------------
// 8 lanes per edge, 32 edges (4 batches) per wave: all 4 pair loads then all
// 8 row gathers issue before any reduction -> 4-deep load ILP hides latency.
// Rows pre-normalized -> dot = cosine.
__global__ void edge_kernel(const uint_t* __restrict__ pair,
                            const float* __restrict__ ew, const ushort_t* __restrict__ xnb,
                            float* __restrict__ cos_out, float* __restrict__ gnn_out, int E) {
    int tid = threadIdx.x;
    int wid = (blockIdx.x * blockDim.x + tid) >> 6;   // global wave id
    int l = tid & 63;
    int g = l >> 3;                                   // edge slot 0..7 in batch
    int j = l & 7;                                    // 16B chunk slot
    int e0 = wid * 32;                                // 32 edges per wave
    if (e0 >= E) return;
    uint_t u[4];
    #pragma unroll
    for (int k = 0; k < 4; ++k) {                     // 4 independent pair loads
        int e = e0 + k * 8 + g;
        u[k] = (e < E) ? pair[e] : pair[E - 1];       // clamp: safe row, store guarded
    }
    uint4 av[4], bv[4];
    #pragma unroll
    for (int k = 0; k < 4; ++k) {                     // 8 independent gathers
        int s = (int)(u[k] & 0xffffu);
        int d = (int)(u[k] >> 16);
        if (j < 5) {                                  // rows are 80B = 5 x 16B
            av[k] = *(const uint4*)(xnb + (size_t)s * CLS + j * 8);
            bv[k] = *(const uint4*)(xnb + (size_t)d * CLS + j * 8);
        }
    }
    #pragma unroll
    for (int k = 0; k < 4; ++k) {                     // reduce + store per batch
        float part = 0.f;
        if (j < 5) part = dot_u4(av[k], bv[k]);
        part += __shfl_xor(part, 1);
        part += __shfl_xor(part, 2);
        part += __shfl_xor(part, 4);
        int e = e0 + k * 8 + g;
        if (j == 0 && e < E) {                        // 8 leaders: 32B coalesced
            cos_out[e] = 1.0f - part;
            gnn_out[e] = (ew[e] > 0.5f) ? 1.0f : -1.0f;
        }
    }
}

// ---------------------------------------------------------------------------
extern "C" void kernel_launch(void* const* d_in, const int* in_sizes, int n_in,
                              void* d_out, int out_size, void* d_ws, size_t ws_size,
                              hipStream_t stream) {
    const float* x   = (const float*)d_in[0];
    const void*  ei  = d_in[1];
    const float* ew  = (const float*)d_in[2];
    const float* W1  = (const float*)d_in[3];
    const float* b1  = (const float*)d_in[4];
    const float* W2  = (const float*)d_in[5];
    const float* b2  = (const float*)d_in[6];

    const int n = in_sizes[0] / F_IN;        // 50000
    const int E = in_sizes[2];               // 1600000

    // output segments (return order)
    float* lsm  = (float*)d_out;                                   // [n*CLS]
    float* xout = lsm + (size_t)n * CLS;                           // [n*CLS]
    float* cosO = xout + (size_t)n * CLS;                          // [E]
    float* gnnO = cosO + E;                                        // [E]
    float* smO  = gnnO + E;                                        // [n*CLS]

    // workspace layout (256B aligned)
    char* w = (char*)d_ws;
    auto alloc = [&](size_t bytes) {
        char* p = w;
        w += (bytes + 255) & ~(size_t)255;
        return p;
    };
    const int NBLK  = (E + EPB - 1) / EPB;   // 196 hist/scatter blocks
    const int NBUCK = (n + 255) / 256;       // 196 buckets (dst>>8)

    uint_t*   pair   = (uint_t*)  alloc((size_t)E * 4);
    uint_t*   bkt    = (uint_t*)  alloc((size_t)E * 4);
    ushort_t* csr16  = (ushort_t*)alloc((size_t)E * 2);
    int*      ghist  = (int*)     alloc((size_t)NBLK * 256 * 4);
    int*      btot   = (int*)     alloc(256 * 4);
    int*      bbase  = (int*)     alloc(257 * 4);
    int*      rowptr = (int*)     alloc(((size_t)n + 1) * 4);
    float*    dinv   = (float*)   alloc((size_t)n * 4);
    ushort_t* xws    = (ushort_t*)alloc((size_t)n * HID * 2);
    ushort_t* hbuf   = (ushort_t*)alloc((size_t)n * HID * 2);   // h rows (bf16)
    ushort_t* hws    = (ushort_t*)alloc((size_t)n * HID * 2);   // padded to 64 ch
    ushort_t* xnb    = (ushort_t*)alloc((size_t)n * CLS * 2);   // normalized rows
    ushort_t* W1s    = (ushort_t*)alloc((size_t)4 * 8 * 64 * 8 * 2);   // 32 KB
    ushort_t* W2s    = (ushort_t*)alloc((size_t)4 * 2 * 64 * 8 * 2);   // 8 KB
    int*      flag   = (int*)     alloc(64);

    detect_kernel<<<1, 64, 0, stream>>>((const int*)ei, flag);
    convert_w1_kernel<<<8, 256, 0, stream>>>(W1, W1s);
    convert_w2_kernel<<<2, 256, 0, stream>>>(W2, W2s);
    build_hist_kernel<<<NBLK, 256, 0, stream>>>(ei, flag, pair, ghist, E);
    scan_cols_kernel<<<256, 64, 0, stream>>>(ghist, btot, NBLK);
    scan_base_kernel<<<1, 256, 0, stream>>>(btot, bbase);
    scatter_buckets_kernel<<<NBLK, 256, 0, stream>>>(pair, ghist, bbase, bkt, E);
    bucket_csr_kernel<<<NBUCK, 256, 0, stream>>>(bkt, bbase, csr16, rowptr, dinv, n, E, NBUCK);
    gemm1_mfma_kernel<<<(n + 15) / 16, 256, 0, stream>>>(x, W1s, dinv, xws, n);
    gather1_kernel<<<((size_t)n * 64 + 255) / 256, 256, 0, stream>>>(rowptr, csr16, xws, dinv,
                                                                     b1, hbuf, n);
    gemm2_mfma_kernel<<<(n + 15) / 16, 256, 0, stream>>>(hbuf, W2s, dinv, hws, n);
    gather2_fin_kernel<<<((size_t)n * 64 + 255) / 256, 256, 0, stream>>>(rowptr, csr16, hws, dinv, b2,
                                                                         xout, lsm, smO, xnb, n);
    edge_kernel<<<((size_t)((E + 31) / 32) * 64 + 255) / 256, 256, 0, stream>>>(pair, ew, xnb, cosO, gnnO, E);
}